// Round 17
// baseline (852.666 us; speedup 1.0000x reference)
//
#include <hip/hip_runtime.h>

#define NB 16
#define NL 4096
#define NDO 1024
#define NH 512
#define NM (NB*NL)          // 65536 rows
#define NK 1024             // K for both GEMMs
#define NN 1024             // N for both GEMMs
#define CH 128
#define NCHUNK (NL/CH)      // 32
#define YCOUNT ((size_t)NM*NDO)   // 67108864
#define HCOUNT ((size_t)NB*NH)    // 8192

typedef unsigned short u16;
typedef float f32x4 __attribute__((ext_vector_type(4)));
typedef unsigned int u32x4 __attribute__((ext_vector_type(4)));
typedef __bf16 bf16x8 __attribute__((ext_vector_type(8)));

__device__ __forceinline__ u16 f2bf(float f){
  unsigned u = __float_as_uint(f);
  unsigned r = u + 0x7fffu + ((u >> 16) & 1u);   // round-to-nearest-even
  return (u16)(r >> 16);
}
__device__ __forceinline__ float bf2f(u16 v){ return __uint_as_float(((unsigned)v) << 16); }
__device__ __forceinline__ unsigned pack2(float a, float b){
  return (unsigned)f2bf(a) | ((unsigned)f2bf(b) << 16);
}

// async global->LDS, 16B per lane; LDS dest = wave-uniform base + lane*16
__device__ __forceinline__ void gld_lds16(const u16* g, u16* l){
  __builtin_amdgcn_global_load_lds(
      (const __attribute__((address_space(1))) unsigned int*)g,
      (__attribute__((address_space(3))) unsigned int*)l,
      16, 0, 0);
}

// ---------------- prep kernels ----------------

__global__ void prep_w1(const float* __restrict__ Bre, const float* __restrict__ Bim,
                        const float* __restrict__ gl, u16* __restrict__ W1){
  int i = blockIdx.x * blockDim.x + threadIdx.x;
  if (i >= NH * NDO) return;
  int h = i / NDO, d = i % NDO;
  float g = expf(gl[h]);
  W1[(size_t)h * NK + d]        = f2bf(Bre[i] * g);
  W1[(size_t)(NH + h) * NK + d] = f2bf(Bim[i] * g);
}

__global__ void prep_w2(const float* __restrict__ Cre, const float* __restrict__ Cim,
                        u16* __restrict__ W2){
  int i = blockIdx.x * blockDim.x + threadIdx.x;
  if (i >= NDO * NH) return;
  int o = i / NH, k = i % NH;
  W2[(size_t)o * NK + k]      = f2bf(Cre[i]);
  W2[(size_t)o * NK + NH + k] = f2bf(-Cim[i]);
}

__global__ void prep_lam(const float* __restrict__ theta_log, const float* __restrict__ nu_log,
                         float* __restrict__ lam){
  int h = threadIdx.x;
  if (h >= NH) return;
  float nu = expf(nu_log[h]);
  float th = expf(theta_log[h]);
  float mag = expf(-nu);
  float lre = mag * cosf(th), lim = mag * sinf(th);
  double pre = (double)lre, pim = (double)lim;
  #pragma unroll
  for (int s = 0; s < 7; s++){
    double nr = pre*pre - pim*pim;
    double ni = 2.0*pre*pim;
    pre = nr; pim = ni;
  }
  lam[h]        = lre;
  lam[NH + h]   = lim;
  lam[2*NH + h] = (float)pre;
  lam[3*NH + h] = (float)pim;
}

// X f32 -> Xb bf16, 8 elements/thread
__global__ __launch_bounds__(256) void convert_x(const float* __restrict__ X, u16* __restrict__ Xb){
  size_t i = ((size_t)blockIdx.x * 256 + threadIdx.x) * 8;
  f32x4 a = *(const f32x4*)(X + i);
  f32x4 b = *(const f32x4*)(X + i + 4);
  u32x4 p;
  p[0] = pack2(a[0], a[1]); p[1] = pack2(a[2], a[3]);
  p[2] = pack2(b[0], b[1]); p[3] = pack2(b[2], b[3]);
  *(u32x4*)(Xb + i) = p;
}

// ================= 256x256 8-wave GEMM, BK=64, stage-ahead-1, swizzled LDS =================
// Round-8/9 kernel (correctness-verified: absmax 0.0625, bank conflicts 0) with the
// REGISTER FIX: __launch_bounds__(512, 1) -> min 1 wave/EU -> VGPR cap 512/wave.
// (512,2)'s cap of 256 still produced VGPR_Count=128 + 1GB scratch spill (rounds 8-9);
// demand is ~200 regs (acc[8][4]=128 + 12 frags + addressing), fits under 512.
// A 512-thread block is 8 waves = 2/SIMD either way, so occupancy is unchanged.

__device__ __forceinline__ void stage_tile(const u16* Ag, const u16* Bg, int kt,
                                           u16 (&AB)[256][64], u16 (&BB)[256][64], int w){
  const u16* a = Ag + (size_t)kt * 64;
  const u16* b = Bg + (size_t)kt * 64;
  #pragma unroll
  for (int s = 0; s < 4; s++){
    gld_lds16(a + (size_t)s * 8 * NK, &AB[w*32 + s*8][0]);
    gld_lds16(b + (size_t)s * 8 * NK, &BB[w*32 + s*8][0]);
  }
}

__device__ __forceinline__ void compute_tile(const u16 (&AB)[256][64], const u16 (&BB)[256][64],
                                             f32x4 (&acc)[8][4], int wr, int wc,
                                             int c15, int sw0, int sw1){
  #pragma unroll
  for (int ks = 0; ks < 2; ks++){
    const int sw = (ks == 0) ? sw0 : sw1;
    bf16x8 af[8], bv[4];
    #pragma unroll
    for (int i = 0; i < 8; i++)
      af[i] = *(const bf16x8*)(&AB[wr*128 + i*16 + c15][0] + sw);
    #pragma unroll
    for (int j = 0; j < 4; j++)
      bv[j] = *(const bf16x8*)(&BB[wc*64 + j*16 + c15][0] + sw);
    #pragma unroll
    for (int i = 0; i < 8; i++)
      #pragma unroll
      for (int j = 0; j < 4; j++)
        acc[i][j] = __builtin_amdgcn_mfma_f32_16x16x32_bf16(af[i], bv[j], acc[i][j], 0, 0, 0);
  }
}

// MODE 0: out = bf16 Bu.
template<int MODE>
__global__ __launch_bounds__(512, 1) void gemm_256(const u16* __restrict__ A,
                                                   const u16* __restrict__ W,
                                                   const float* __restrict__ Xf,
                                                   const u16* __restrict__ Xh,
                                                   const float* __restrict__ Dv,
                                                   u16* __restrict__ outB,
                                                   float* __restrict__ outF){
  __shared__ __align__(16) u16 A0[256][64];   // 32 KiB each; 128 KiB total
  __shared__ __align__(16) u16 B0[256][64];
  __shared__ __align__(16) u16 A1[256][64];
  __shared__ __align__(16) u16 B1[256][64];
  const int tid = threadIdx.x;
  // XCD swizzle: 1024 blocks, 8 XCDs, 128 contiguous lids each.
  const int bid = blockIdx.x;
  const int lid = (bid & 7) * 128 + (bid >> 3);
  const int m0 = (lid >> 2) << 8;     // 256 m-tiles
  const int n0 = (lid & 3) << 8;      // 4 n-tiles
  const int w = tid >> 6, lane = tid & 63;
  const int wr = w >> 2, wc = w & 3;  // 2 x 4 wave grid; wave output 128 x 64

  // staging source: lane -> row (lane>>3) of an 8-row DMA block, pre-swizzled granule
  const int grow = lane >> 3;                       // 0..7
  const int gcol = ((lane & 7) ^ grow) << 3;        // swizzled 8-elem (16B) granule
  const u16* Ag = A + (size_t)(m0 + w*32 + grow) * NK + gcol;
  const u16* Bg = W + (size_t)(n0 + w*32 + grow) * NK + gcol;

  // fragment-read constants (swizzled column offsets, static per lane)
  const int c15 = lane & 15;
  const int qb  = lane >> 4;                        // 0..3
  const int sw0 = ((qb    ) ^ (lane & 7)) << 3;     // ks=0 col offset (elems)
  const int sw1 = ((qb | 4) ^ (lane & 7)) << 3;     // ks=1

  f32x4 acc[8][4];
  #pragma unroll
  for (int m = 0; m < 8; m++)
    #pragma unroll
    for (int n = 0; n < 4; n++) acc[m][n] = (f32x4){0.f,0.f,0.f,0.f};

#define LGKM0_() asm volatile("s_waitcnt lgkmcnt(0)" ::: "memory")
#define VM0_()   asm volatile("s_waitcnt vmcnt(0)" ::: "memory")
#define BAR_()   __builtin_amdgcn_s_barrier()

  // prologue: tile 0 -> buf0
  stage_tile(Ag, Bg, 0, A0, B0, w);
  VM0_();
  BAR_();

  #pragma unroll 1
  for (int kt = 0; kt < NK/64; kt += 2){
    // even tile kt from buf0; stage kt+1 -> buf1
    stage_tile(Ag, Bg, kt + 1, A1, B1, w);
    compute_tile(A0, B0, acc, wr, wc, c15, sw0, sw1);
    LGKM0_();                // my reads of buf0 done
    BAR_();                  // all waves' reads of buf0 done
    VM0_();                  // my staged loads (tile kt+1) landed
    BAR_();                  // everyone's landed
    // odd tile kt+1 from buf1; stage kt+2 -> buf0
    if (kt + 2 < NK/64){
      stage_tile(Ag, Bg, kt + 2, A0, B0, w);
      compute_tile(A1, B1, acc, wr, wc, c15, sw0, sw1);
      LGKM0_(); BAR_();
      VM0_();  BAR_();
    } else {
      compute_tile(A1, B1, acc, wr, wc, c15, sw0, sw1);
    }
  }

#undef LGKM0_
#undef VM0_
#undef BAR_

  const int r4 = (lane >> 4) << 2;
  #pragma unroll
  for (int m = 0; m < 8; m++){
    int gm = m0 + wr*128 + m*16 + r4;
    #pragma unroll
    for (int n = 0; n < 4; n++){
      int gn = n0 + wc*64 + n*16 + c15;
      if constexpr (MODE == 0) {
        #pragma unroll
        for (int r = 0; r < 4; r++)
          outB[(size_t)(gm + r) * NN + gn] = f2bf(acc[m][n][r]);
      } else if constexpr (MODE == 1) {
        float dv = Dv[gn];
        #pragma unroll
        for (int r = 0; r < 4; r++){
          size_t oidx = (size_t)(gm + r) * NDO + gn;
          outF[oidx] = acc[m][n][r] + dv * Xf[oidx];
        }
      } else {
        float dv = Dv[gn];
        #pragma unroll
        for (int r = 0; r < 4; r++){
          size_t oidx = (size_t)(gm + r) * NDO + gn;
          outF[oidx] = acc[m][n][r] + dv * bf2f(Xh[oidx]);
        }
      }
    }
  }
}

// ==== verified swizzled 128x128 GEMM (rounds 11-15: ~223 us, 0 bank conflicts) ====
// MODE 0: out = bf16 Bu.  MODE 1: f32 Y = acc + Dv*X(f32).  MODE 2: f32 Y = acc + Dv*Xb(bf16).

#define STG_PAIR(AT, BT, t) do {                                 \
    _Pragma("unroll")                                            \
    for (int s = 0; s < 4; s++){                                 \
      gld_lds16(Ag + (size_t)(t)*64 + (size_t)s*8*NK, &AT[w*32 + s*8][0]); \
      gld_lds16(Bg + (size_t)(t)*64 + (size_t)s*8*NK, &BT[w*32 + s*8][0]); \
    }                                                            \
  } while(0)
#define CMP_TILE(AT, BT) do {                                       \
    bf16x8 af[4][2], bv[4][2];                                      \
    _Pragma("unroll")                                               \
    for (int i = 0; i < 4; i++){                                    \
      const u16* pa = &AT[rowa + i*16][0];                          \
      const u16* pb = &BT[rowb + i*16][0];                          \
      af[i][0] = *(const bf16x8*)(pa + sw0);                        \
      af[i][1] = *(const bf16x8*)(pa + sw1);                        \
      bv[i][0] = *(const bf16x8*)(pb + sw0);                        \
      bv[i][1] = *(const bf16x8*)(pb + sw1);                        \
    }                                                               \
    _Pragma("unroll")                                               \
    for (int i = 0; i < 4; i++)                                     \
      _Pragma("unroll")                                             \
      for (int j = 0; j < 4; j++){                                  \
        acc[i][j] = __builtin_amdgcn_mfma_f32_16x16x32_bf16(af[i][0], bv[j][0], acc[i][j], 0, 0, 0); \
        acc[i][j] = __builtin_amdgcn_mfma_f32_16x16x32_bf16(af[i][1], bv[j][1], acc[i][j], 0, 0, 0); \
      }                                                             \
  } while(0)
#define WVM(n)  asm volatile("s_waitcnt vmcnt(" #n ")" ::: "memory")
#define LGKM0() asm volatile("s_waitcnt lgkmcnt(0)" ::: "memory")
#define BARR()  asm volatile("s_barrier" ::: "memory")

template<int MODE>
__global__ __launch_bounds__(256) void gemm_sz(const u16* __restrict__ A,
                                               const u16* __restrict__ W,
                                               const float* __restrict__ Xf,
                                               const u16* __restrict__ Xh,
                                               const float* __restrict__ Dv,
                                               u16* __restrict__ outB,
                                               float* __restrict__ outF){
  __shared__ __align__(16) u16 A0[128][64];
  __shared__ __align__(16) u16 B0[128][64];
  __shared__ __align__(16) u16 A1[128][64];
  __shared__ __align__(16) u16 B1[128][64];
  const int tid = threadIdx.x;
  const int bid = blockIdx.x;
  const int lid = (bid & 7) * 512 + (bid >> 3);
  const int m0 = (lid >> 3) << 7;
  const int n0 = (lid & 7) << 7;
  const int w = tid >> 6, lane = tid & 63;
  const int wm = w >> 1, wn = w & 1;

  const int grow = lane >> 3;
  const int gcol = ((lane & 7) ^ grow) << 3;
  const u16* Ag = A + (size_t)(m0 + w*32 + grow) * NK + gcol;
  const u16* Bg = W + (size_t)(n0 + w*32 + grow) * NK + gcol;

  f32x4 acc[4][4];
#pragma unroll
  for (int i = 0; i < 4; i++)
#pragma unroll
    for (int j = 0; j < 4; j++) acc[i][j] = (f32x4){0.f,0.f,0.f,0.f};

  const int c15 = lane & 15;
  const int q   = lane >> 4;
  const int sw0 = ((q    ) ^ (lane & 7)) << 3;
  const int sw1 = ((q | 4) ^ (lane & 7)) << 3;
  const int rowa = wm*64 + c15;
  const int rowb = wn*64 + c15;

  STG_PAIR(A0, B0, 0);
  STG_PAIR(A1, B1, 1);
  WVM(8);
  BARR();
  for (int t = 0; t < 14; t += 2) {
    CMP_TILE(A0, B0);
    LGKM0();
    BARR();
    STG_PAIR(A0, B0, t + 2);
    WVM(8);
    BARR();
    CMP_TILE(A1, B1);
    LGKM0();
    BARR();
    STG_PAIR(A1, B1, t + 3);
    WVM(8);
    BARR();
  }
  CMP_TILE(A0, B0);
  WVM(0);
  BARR();
  CMP_TILE(A1, B1);

  const int r0 = (lane >> 4) << 2;
#pragma unroll
  for (int i = 0; i < 4; i++){
    int gm = m0 + wm*64 + i*16 + r0;
#pragma unroll
    for (int j = 0; j < 4; j++){
      int gn = n0 + wn*64 + j*16 + c15;
      if constexpr (MODE == 0) {
#pragma unroll
        for (int r = 0; r < 4; r++)
          outB[(size_t)(gm + r) * NN + gn] = f2bf(acc[i][j][r]);
      } else if constexpr (MODE == 1) {
        float dv = Dv[gn];
#pragma unroll
        for (int r = 0; r < 4; r++){
          size_t oidx = (size_t)(gm + r) * NDO + gn;
          outF[oidx] = acc[i][j][r] + dv * Xf[oidx];
        }
      } else {
        float dv = Dv[gn];
#pragma unroll
        for (int r = 0; r < 4; r++){
          size_t oidx = (size_t)(gm + r) * NDO + gn;
          outF[oidx] = acc[i][j][r] + dv * bf2f(Xh[oidx]);
        }
      }
    }
  }
}

// ---------------- legacy GEMM1 (f32 A reg-pack) — fallback if ws too small ----------------

__global__ __launch_bounds__(256) void gemm1_legacy(const float* __restrict__ X,
                                                    const u16* __restrict__ W1,
                                                    u16* __restrict__ Bu){
  __shared__ __align__(16) u16 Alds[128][32];
  __shared__ __align__(16) u16 Blds[128][32];
  const int tid = threadIdx.x;
  const int bid = blockIdx.x;
  const int lid = (bid & 7) * 512 + (bid >> 3);
  const int m0 = (lid >> 3) << 7;
  const int n0 = (lid & 7) << 7;
  const int w = tid >> 6, lane = tid & 63;
  const int wm = w >> 1, wn = w & 1;
  f32x4 acc[4][4];
#pragma unroll
  for (int i = 0; i < 4; i++)
#pragma unroll
    for (int j = 0; j < 4; j++) acc[i][j] = (f32x4){0.f,0.f,0.f,0.f};

  const int srow = tid >> 1;
  const int skseg = (tid & 1) << 4;
  const float* xp = X + (size_t)(m0 + srow) * NK + skseg;
  const u16*  wp  = W1 + (size_t)(n0 + srow) * NK + skseg;

  const int klane = (lane >> 4) << 3;
  const int rowa = wm*64 + (lane & 15);
  const int rowb = wn*64 + (lane & 15);

  for (int k0 = 0; k0 < NK; k0 += 32) {
    __syncthreads();
    f32x4 v0 = *(const f32x4*)(xp + k0 + 0);
    f32x4 v1 = *(const f32x4*)(xp + k0 + 4);
    f32x4 v2 = *(const f32x4*)(xp + k0 + 8);
    f32x4 v3 = *(const f32x4*)(xp + k0 + 12);
    u32x4 q0 = *(const u32x4*)(wp + k0);
    u32x4 q1 = *(const u32x4*)(wp + k0 + 8);
    u32x4 p0, p1;
    p0[0] = pack2(v0[0], v0[1]); p0[1] = pack2(v0[2], v0[3]);
    p0[2] = pack2(v1[0], v1[1]); p0[3] = pack2(v1[2], v1[3]);
    p1[0] = pack2(v2[0], v2[1]); p1[1] = pack2(v2[2], v2[3]);
    p1[2] = pack2(v3[0], v3[1]); p1[3] = pack2(v3[2], v3[3]);
    *(u32x4*)&Alds[srow][skseg]     = p0;
    *(u32x4*)&Alds[srow][skseg + 8] = p1;
    *(u32x4*)&Blds[srow][skseg]     = q0;
    *(u32x4*)&Blds[srow][skseg + 8] = q1;
    __syncthreads();
    bf16x8 af[4], bv[4];
#pragma unroll
    for (int i = 0; i < 4; i++){
      af[i] = *(const bf16x8*)&Alds[rowa + i*16][klane];
      bv[i] = *(const bf16x8*)&Blds[rowb + i*16][klane];
    }
#pragma unroll
    for (int i = 0; i < 4; i++)
#pragma unroll
      for (int j = 0; j < 4; j++)
        acc[i][j] = __builtin_amdgcn_mfma_f32_16x16x32_bf16(af[i], bv[j], acc[i][j], 0, 0, 0);
  }

  const int r0 = (lane >> 4) << 2;
  const int col = lane & 15;
#pragma unroll
  for (int i = 0; i < 4; i++){
    int gm = m0 + wm*64 + i*16 + r0;
#pragma unroll
    for (int j = 0; j < 4; j++){
      int gn = n0 + wn*64 + j*16 + col;
#pragma unroll
      for (int r = 0; r < 4; r++)
        Bu[(size_t)(gm + r) * NN + gn] = f2bf(acc[i][j][r]);
    }
  }
}

// ---------------- scan kernels (verified rounds 2-12) ----------------

__global__ __launch_bounds__(512) void scan_carry(const u16* __restrict__ Bu,
                                                  const float* __restrict__ lam,
                                                  float* __restrict__ carry){
  const int h = threadIdx.x;
  const int bc = blockIdx.x;
  const int b = bc / NCHUNK, c = bc % NCHUNK;
  const float lre = lam[h], lim = lam[NH + h];
  float hre = 0.f, him = 0.f;
  size_t base = (size_t)(b * NL + c * CH) * NN;
  for (int j = 0; j < CH; j++){
    float bre = bf2f(Bu[base + (size_t)j*NN + h]);
    float bim = bf2f(Bu[base + (size_t)j*NN + NH + h]);
    float nre = lre*hre - lim*him + bre;
    float nim = lre*him + lim*hre + bim;
    hre = nre; him = nim;
  }
  size_t ci = ((size_t)bc * NH + h) * 2;
  carry[ci] = hre; carry[ci + 1] = him;
}

__global__ __launch_bounds__(512) void scan_combine(const float* __restrict__ carry,
                                                    const float* __restrict__ lam,
                                                    float* __restrict__ hstart){
  const int h = threadIdx.x;
  const int b = blockIdx.x;
  const float Pre = lam[2*NH + h], Pim = lam[3*NH + h];
  float are = 0.f, aim = 0.f;
  for (int c = 0; c < NCHUNK; c++){
    size_t idx = ((size_t)(b * NCHUNK + c) * NH + h) * 2;
    hstart[idx] = are; hstart[idx + 1] = aim;
    float cre = carry[idx], cim = carry[idx + 1];
    float nre = Pre*are - Pim*aim + cre;
    float nim = Pre*aim + Pim*are + cim;
    are = nre; aim = nim;
  }
}

__global__ __launch_bounds__(512) void scan_fixup_full(u16* __restrict__ Bu,
                                                       const float* __restrict__ lam,
                                                       const float* __restrict__ hstart,
                                                       float* __restrict__ out, int out_size){
  const int h = threadIdx.x;
  const int bc = blockIdx.x;
  const int b = bc / NCHUNK, c = bc % NCHUNK;
  const float lre = lam[h], lim = lam[NH + h];
  size_t si = ((size_t)bc * NH + h) * 2;
  const float sre = hstart[si], sim = hstart[si + 1];
  float hre = 0.f, him = 0.f;
  float pre = lre, pim = lim;
  size_t base = (size_t)(b * NL + c * CH) * NN;
  for (int j = 0; j < CH; j++){
    float bre = bf2f(Bu[base + (size_t)j*NN + h]);
    float bim = bf2f(Bu[base + (size_t)j*NN + NH + h]);
    float nre = lre*hre - lim*him + bre;
    float nim = lre*him + lim*hre + bim;
    hre = nre; him = nim;
    float vre = hre + pre*sre - pim*sim;
    float vim = him + pre*sim + pim*sre;
    Bu[base + (size_t)j*NN + h]      = f2bf(vre);
    Bu[base + (size_t)j*NN + NH + h] = f2bf(vim);
    if (c == NCHUNK - 1 && j == CH - 1){
      size_t ore_i = YCOUNT + (size_t)b * NH + h;
      size_t oim_i = YCOUNT + HCOUNT + (size_t)b * NH + h;
      if (ore_i < (size_t)out_size) out[ore_i] = vre;
      if (oim_i < (size_t)out_size) out[oim_i] = vim;
    }
    float qre = pre*lre - pim*lim;
    float qim = pre*lim + pim*lre;
    pre = qre; pim = qim;
  }
}

// ---------------- launch ----------------

extern "C" void kernel_launch(void* const* d_in, const int* in_sizes, int n_in,
                              void* d_out, int out_size, void* d_ws, size_t ws_size,
                              hipStream_t stream) {
  const float* x         = (const float*)d_in[0];
  const float* theta_log = (const float*)d_in[1];
  const float* nu_log    = (const float*)d_in[2];
  const float* gamma_log = (const float*)d_in[3];
  const float* Bre       = (const float*)d_in[4];
  const float* Bim       = (const float*)d_in[5];
  const float* Cre       = (const float*)d_in[6];
  const float* Cim       = (const float*)d_in[7];
  const float* Dv        = (const float*)d_in[8];
  float* out = (float*)d_out;
  char* ws = (char*)d_ws;

  // workspace layout
  u16*   W1     = (u16*)(ws);                        // 2 MiB
  u16*   W2     = (u16*)(ws + (2u << 20));           // 2 MiB
  float* lam    = (float*)(ws + (4u << 20));         // 8 KiB
  float* carry  = (float*)(ws + (5u << 20));         // 2 MiB
  float* hstart = (float*)(ws + (7u << 20));         // 2 MiB
  u16*   Bu     = (u16*)(ws + (16u << 20));          // 128 MiB
  u16*   Xb     = (u16*)(ws + (144u << 20));         // 128 MiB (fast path only)
  size_t need_base = (16u << 20) + (size_t)NM * NN * 2;           // 144 MiB
  size_t need_fast = need_base + (size_t)NM * NK * 2;             // 272 MiB
  if (ws_size < need_base) return;
  const bool fast = (ws_size >= need_fast);

  prep_w1<<<(NH * NDO + 255) / 256, 256, 0, stream>>>(Bre, Bim, gamma_log, W1);
  prep_w2<<<(NDO * NH + 255) / 256, 256, 0, stream>>>(Cre, Cim, W2);
  prep_lam<<<1, 512, 0, stream>>>(theta_log, nu_log, lam);

  const int g256 = (NM / 256) * (NN / 256);   // 1024 blocks

  if (fast) {
    convert_x<<<(int)(YCOUNT / (256*8)), 256, 0, stream>>>(x, Xb);
    // A/B probe: gemm1 = 256x256 with register fix (512,1); gemm2 = gemm_sz control
    gemm_256<0><<<g256, 512, 0, stream>>>(Xb, W1, nullptr, nullptr, nullptr, Bu, nullptr);
  } else {
    gemm1_legacy<<<4096, 256, 0, stream>>>(x, W1, Bu);
  }

  scan_carry<<<NB * NCHUNK, 512, 0, stream>>>(Bu, lam, carry);
  scan_combine<<<NB, 512, 0, stream>>>(carry, lam, hstart);
  scan_fixup_full<<<NB * NCHUNK, 512, 0, stream>>>(Bu, lam, hstart, out, out_size);

  if (fast) {
    gemm_sz<2><<<4096, 256, 0, stream>>>(Bu, W2, nullptr, Xb, Dv, nullptr, out);
  } else {
    gemm_sz<1><<<4096, 256, 0, stream>>>(Bu, W2, x, nullptr, Dv, nullptr, out);
  }
}

// Round 18
// 851.521 us; speedup vs baseline: 1.0013x; 1.0013x over previous
//
#include <hip/hip_runtime.h>

#define NB 16
#define NL 4096
#define NDO 1024
#define NH 512
#define NM (NB*NL)          // 65536 rows
#define NK 1024             // K for both GEMMs
#define NN 1024             // N for both GEMMs
#define CH 128
#define NCHUNK (NL/CH)      // 32
#define YCOUNT ((size_t)NM*NDO)   // 67108864
#define HCOUNT ((size_t)NB*NH)    // 8192

typedef unsigned short u16;
typedef float f32x4 __attribute__((ext_vector_type(4)));
typedef unsigned int u32x4 __attribute__((ext_vector_type(4)));
typedef __bf16 bf16x8 __attribute__((ext_vector_type(8)));

__device__ __forceinline__ u16 f2bf(float f){
  unsigned u = __float_as_uint(f);
  unsigned r = u + 0x7fffu + ((u >> 16) & 1u);   // round-to-nearest-even
  return (u16)(r >> 16);
}
__device__ __forceinline__ float bf2f(u16 v){ return __uint_as_float(((unsigned)v) << 16); }
__device__ __forceinline__ unsigned pack2(float a, float b){
  return (unsigned)f2bf(a) | ((unsigned)f2bf(b) << 16);
}

// async global->LDS, 16B per lane; LDS dest = wave-uniform base + lane*16
__device__ __forceinline__ void gld_lds16(const u16* g, u16* l){
  __builtin_amdgcn_global_load_lds(
      (const __attribute__((address_space(1))) unsigned int*)g,
      (__attribute__((address_space(3))) unsigned int*)l,
      16, 0, 0);
}

// ---------------- prep kernels ----------------

__global__ void prep_w1(const float* __restrict__ Bre, const float* __restrict__ Bim,
                        const float* __restrict__ gl, u16* __restrict__ W1){
  int i = blockIdx.x * blockDim.x + threadIdx.x;
  if (i >= NH * NDO) return;
  int h = i / NDO, d = i % NDO;
  float g = expf(gl[h]);
  W1[(size_t)h * NK + d]        = f2bf(Bre[i] * g);
  W1[(size_t)(NH + h) * NK + d] = f2bf(Bim[i] * g);
}

__global__ void prep_w2(const float* __restrict__ Cre, const float* __restrict__ Cim,
                        u16* __restrict__ W2){
  int i = blockIdx.x * blockDim.x + threadIdx.x;
  if (i >= NDO * NH) return;
  int o = i / NH, k = i % NH;
  W2[(size_t)o * NK + k]      = f2bf(Cre[i]);
  W2[(size_t)o * NK + NH + k] = f2bf(-Cim[i]);
}

__global__ void prep_lam(const float* __restrict__ theta_log, const float* __restrict__ nu_log,
                         float* __restrict__ lam){
  int h = threadIdx.x;
  if (h >= NH) return;
  float nu = expf(nu_log[h]);
  float th = expf(theta_log[h]);
  float mag = expf(-nu);
  float lre = mag * cosf(th), lim = mag * sinf(th);
  double pre = (double)lre, pim = (double)lim;
  #pragma unroll
  for (int s = 0; s < 7; s++){
    double nr = pre*pre - pim*pim;
    double ni = 2.0*pre*pim;
    pre = nr; pim = ni;
  }
  lam[h]        = lre;
  lam[NH + h]   = lim;
  lam[2*NH + h] = (float)pre;
  lam[3*NH + h] = (float)pim;
}

// X f32 -> Xb bf16, 8 elements/thread
__global__ __launch_bounds__(256) void convert_x(const float* __restrict__ X, u16* __restrict__ Xb){
  size_t i = ((size_t)blockIdx.x * 256 + threadIdx.x) * 8;
  f32x4 a = *(const f32x4*)(X + i);
  f32x4 b = *(const f32x4*)(X + i + 4);
  u32x4 p;
  p[0] = pack2(a[0], a[1]); p[1] = pack2(a[2], a[3]);
  p[2] = pack2(b[0], b[1]); p[3] = pack2(b[2], b[3]);
  *(u32x4*)(Xb + i) = p;
}

// ================= 256x256 8-wave GEMM, BK=64, stage-ahead-1, swizzled LDS =================
// Correctness-verified rounds 8/9/17 (absmax 0.0625, bank conflicts 0). Perf was
// killed by accumulator spill: the backend's occupancy heuristic targeted 4 waves/EU
// -> 128-VGPR cap despite launch_bounds. FIX: amdgpu_waves_per_eu(2,2) pins the
// allocator at exactly 2 waves/EU -> 256-VGPR budget; demand (~200) fits, no spill.

__device__ __forceinline__ void stage_tile(const u16* Ag, const u16* Bg, int kt,
                                           u16 (&AB)[256][64], u16 (&BB)[256][64], int w){
  const u16* a = Ag + (size_t)kt * 64;
  const u16* b = Bg + (size_t)kt * 64;
  #pragma unroll
  for (int s = 0; s < 4; s++){
    gld_lds16(a + (size_t)s * 8 * NK, &AB[w*32 + s*8][0]);
    gld_lds16(b + (size_t)s * 8 * NK, &BB[w*32 + s*8][0]);
  }
}

__device__ __forceinline__ void compute_tile(const u16 (&AB)[256][64], const u16 (&BB)[256][64],
                                             f32x4 (&acc)[8][4], int wr, int wc,
                                             int c15, int sw0, int sw1){
  #pragma unroll
  for (int ks = 0; ks < 2; ks++){
    const int sw = (ks == 0) ? sw0 : sw1;
    bf16x8 af[8], bv[4];
    #pragma unroll
    for (int i = 0; i < 8; i++)
      af[i] = *(const bf16x8*)(&AB[wr*128 + i*16 + c15][0] + sw);
    #pragma unroll
    for (int j = 0; j < 4; j++)
      bv[j] = *(const bf16x8*)(&BB[wc*64 + j*16 + c15][0] + sw);
    #pragma unroll
    for (int i = 0; i < 8; i++)
      #pragma unroll
      for (int j = 0; j < 4; j++)
        acc[i][j] = __builtin_amdgcn_mfma_f32_16x16x32_bf16(af[i], bv[j], acc[i][j], 0, 0, 0);
  }
}

// MODE 0: out = bf16 Bu.
template<int MODE>
__global__ __launch_bounds__(512)
__attribute__((amdgpu_waves_per_eu(2, 2)))
void gemm_256(const u16* __restrict__ A,
              const u16* __restrict__ W,
              const float* __restrict__ Xf,
              const u16* __restrict__ Xh,
              const float* __restrict__ Dv,
              u16* __restrict__ outB,
              float* __restrict__ outF){
  __shared__ __align__(16) u16 A0[256][64];   // 32 KiB each; 128 KiB total
  __shared__ __align__(16) u16 B0[256][64];
  __shared__ __align__(16) u16 A1[256][64];
  __shared__ __align__(16) u16 B1[256][64];
  const int tid = threadIdx.x;
  // XCD swizzle: 1024 blocks, 8 XCDs, 128 contiguous lids each.
  const int bid = blockIdx.x;
  const int lid = (bid & 7) * 128 + (bid >> 3);
  const int m0 = (lid >> 2) << 8;     // 256 m-tiles
  const int n0 = (lid & 3) << 8;      // 4 n-tiles
  const int w = tid >> 6, lane = tid & 63;
  const int wr = w >> 2, wc = w & 3;  // 2 x 4 wave grid; wave output 128 x 64

  // staging source: lane -> row (lane>>3) of an 8-row DMA block, pre-swizzled granule
  const int grow = lane >> 3;                       // 0..7
  const int gcol = ((lane & 7) ^ grow) << 3;        // swizzled 8-elem (16B) granule
  const u16* Ag = A + (size_t)(m0 + w*32 + grow) * NK + gcol;
  const u16* Bg = W + (size_t)(n0 + w*32 + grow) * NK + gcol;

  // fragment-read constants (swizzled column offsets, static per lane)
  const int c15 = lane & 15;
  const int qb  = lane >> 4;                        // 0..3
  const int sw0 = ((qb    ) ^ (lane & 7)) << 3;     // ks=0 col offset (elems)
  const int sw1 = ((qb | 4) ^ (lane & 7)) << 3;     // ks=1

  f32x4 acc[8][4];
  #pragma unroll
  for (int m = 0; m < 8; m++)
    #pragma unroll
    for (int n = 0; n < 4; n++) acc[m][n] = (f32x4){0.f,0.f,0.f,0.f};

#define LGKM0_() asm volatile("s_waitcnt lgkmcnt(0)" ::: "memory")
#define VM0_()   asm volatile("s_waitcnt vmcnt(0)" ::: "memory")
#define BAR_()   __builtin_amdgcn_s_barrier()

  // prologue: tile 0 -> buf0
  stage_tile(Ag, Bg, 0, A0, B0, w);
  VM0_();
  BAR_();

  #pragma unroll 1
  for (int kt = 0; kt < NK/64; kt += 2){
    // even tile kt from buf0; stage kt+1 -> buf1
    stage_tile(Ag, Bg, kt + 1, A1, B1, w);
    compute_tile(A0, B0, acc, wr, wc, c15, sw0, sw1);
    LGKM0_();                // my reads of buf0 done
    BAR_();                  // all waves' reads of buf0 done
    VM0_();                  // my staged loads (tile kt+1) landed
    BAR_();                  // everyone's landed
    // odd tile kt+1 from buf1; stage kt+2 -> buf0
    if (kt + 2 < NK/64){
      stage_tile(Ag, Bg, kt + 2, A0, B0, w);
      compute_tile(A1, B1, acc, wr, wc, c15, sw0, sw1);
      LGKM0_(); BAR_();
      VM0_();  BAR_();
    } else {
      compute_tile(A1, B1, acc, wr, wc, c15, sw0, sw1);
    }
  }

#undef LGKM0_
#undef VM0_
#undef BAR_

  const int r4 = (lane >> 4) << 2;
  #pragma unroll
  for (int m = 0; m < 8; m++){
    int gm = m0 + wr*128 + m*16 + r4;
    #pragma unroll
    for (int n = 0; n < 4; n++){
      int gn = n0 + wc*64 + n*16 + c15;
      if constexpr (MODE == 0) {
        #pragma unroll
        for (int r = 0; r < 4; r++)
          outB[(size_t)(gm + r) * NN + gn] = f2bf(acc[m][n][r]);
      } else if constexpr (MODE == 1) {
        float dv = Dv[gn];
        #pragma unroll
        for (int r = 0; r < 4; r++){
          size_t oidx = (size_t)(gm + r) * NDO + gn;
          outF[oidx] = acc[m][n][r] + dv * Xf[oidx];
        }
      } else {
        float dv = Dv[gn];
        #pragma unroll
        for (int r = 0; r < 4; r++){
          size_t oidx = (size_t)(gm + r) * NDO + gn;
          outF[oidx] = acc[m][n][r] + dv * bf2f(Xh[oidx]);
        }
      }
    }
  }
}

// ==== verified swizzled 128x128 GEMM (rounds 11-15: ~223 us, 0 bank conflicts) ====
// MODE 0: out = bf16 Bu.  MODE 1: f32 Y = acc + Dv*X(f32).  MODE 2: f32 Y = acc + Dv*Xb(bf16).

#define STG_PAIR(AT, BT, t) do {                                 \
    _Pragma("unroll")                                            \
    for (int s = 0; s < 4; s++){                                 \
      gld_lds16(Ag + (size_t)(t)*64 + (size_t)s*8*NK, &AT[w*32 + s*8][0]); \
      gld_lds16(Bg + (size_t)(t)*64 + (size_t)s*8*NK, &BT[w*32 + s*8][0]); \
    }                                                            \
  } while(0)
#define CMP_TILE(AT, BT) do {                                       \
    bf16x8 af[4][2], bv[4][2];                                      \
    _Pragma("unroll")                                               \
    for (int i = 0; i < 4; i++){                                    \
      const u16* pa = &AT[rowa + i*16][0];                          \
      const u16* pb = &BT[rowb + i*16][0];                          \
      af[i][0] = *(const bf16x8*)(pa + sw0);                        \
      af[i][1] = *(const bf16x8*)(pa + sw1);                        \
      bv[i][0] = *(const bf16x8*)(pb + sw0);                        \
      bv[i][1] = *(const bf16x8*)(pb + sw1);                        \
    }                                                               \
    _Pragma("unroll")                                               \
    for (int i = 0; i < 4; i++)                                     \
      _Pragma("unroll")                                             \
      for (int j = 0; j < 4; j++){                                  \
        acc[i][j] = __builtin_amdgcn_mfma_f32_16x16x32_bf16(af[i][0], bv[j][0], acc[i][j], 0, 0, 0); \
        acc[i][j] = __builtin_amdgcn_mfma_f32_16x16x32_bf16(af[i][1], bv[j][1], acc[i][j], 0, 0, 0); \
      }                                                             \
  } while(0)
#define WVM(n)  asm volatile("s_waitcnt vmcnt(" #n ")" ::: "memory")
#define LGKM0() asm volatile("s_waitcnt lgkmcnt(0)" ::: "memory")
#define BARR()  asm volatile("s_barrier" ::: "memory")

template<int MODE>
__global__ __launch_bounds__(256) void gemm_sz(const u16* __restrict__ A,
                                               const u16* __restrict__ W,
                                               const float* __restrict__ Xf,
                                               const u16* __restrict__ Xh,
                                               const float* __restrict__ Dv,
                                               u16* __restrict__ outB,
                                               float* __restrict__ outF){
  __shared__ __align__(16) u16 A0[128][64];
  __shared__ __align__(16) u16 B0[128][64];
  __shared__ __align__(16) u16 A1[128][64];
  __shared__ __align__(16) u16 B1[128][64];
  const int tid = threadIdx.x;
  const int bid = blockIdx.x;
  const int lid = (bid & 7) * 512 + (bid >> 3);
  const int m0 = (lid >> 3) << 7;
  const int n0 = (lid & 7) << 7;
  const int w = tid >> 6, lane = tid & 63;
  const int wm = w >> 1, wn = w & 1;

  const int grow = lane >> 3;
  const int gcol = ((lane & 7) ^ grow) << 3;
  const u16* Ag = A + (size_t)(m0 + w*32 + grow) * NK + gcol;
  const u16* Bg = W + (size_t)(n0 + w*32 + grow) * NK + gcol;

  f32x4 acc[4][4];
#pragma unroll
  for (int i = 0; i < 4; i++)
#pragma unroll
    for (int j = 0; j < 4; j++) acc[i][j] = (f32x4){0.f,0.f,0.f,0.f};

  const int c15 = lane & 15;
  const int q   = lane >> 4;
  const int sw0 = ((q    ) ^ (lane & 7)) << 3;
  const int sw1 = ((q | 4) ^ (lane & 7)) << 3;
  const int rowa = wm*64 + c15;
  const int rowb = wn*64 + c15;

  STG_PAIR(A0, B0, 0);
  STG_PAIR(A1, B1, 1);
  WVM(8);
  BARR();
  for (int t = 0; t < 14; t += 2) {
    CMP_TILE(A0, B0);
    LGKM0();
    BARR();
    STG_PAIR(A0, B0, t + 2);
    WVM(8);
    BARR();
    CMP_TILE(A1, B1);
    LGKM0();
    BARR();
    STG_PAIR(A1, B1, t + 3);
    WVM(8);
    BARR();
  }
  CMP_TILE(A0, B0);
  WVM(0);
  BARR();
  CMP_TILE(A1, B1);

  const int r0 = (lane >> 4) << 2;
#pragma unroll
  for (int i = 0; i < 4; i++){
    int gm = m0 + wm*64 + i*16 + r0;
#pragma unroll
    for (int j = 0; j < 4; j++){
      int gn = n0 + wn*64 + j*16 + c15;
      if constexpr (MODE == 0) {
#pragma unroll
        for (int r = 0; r < 4; r++)
          outB[(size_t)(gm + r) * NN + gn] = f2bf(acc[i][j][r]);
      } else if constexpr (MODE == 1) {
        float dv = Dv[gn];
#pragma unroll
        for (int r = 0; r < 4; r++){
          size_t oidx = (size_t)(gm + r) * NDO + gn;
          outF[oidx] = acc[i][j][r] + dv * Xf[oidx];
        }
      } else {
        float dv = Dv[gn];
#pragma unroll
        for (int r = 0; r < 4; r++){
          size_t oidx = (size_t)(gm + r) * NDO + gn;
          outF[oidx] = acc[i][j][r] + dv * bf2f(Xh[oidx]);
        }
      }
    }
  }
}

// ---------------- legacy GEMM1 (f32 A reg-pack) — fallback if ws too small ----------------

__global__ __launch_bounds__(256) void gemm1_legacy(const float* __restrict__ X,
                                                    const u16* __restrict__ W1,
                                                    u16* __restrict__ Bu){
  __shared__ __align__(16) u16 Alds[128][32];
  __shared__ __align__(16) u16 Blds[128][32];
  const int tid = threadIdx.x;
  const int bid = blockIdx.x;
  const int lid = (bid & 7) * 512 + (bid >> 3);
  const int m0 = (lid >> 3) << 7;
  const int n0 = (lid & 7) << 7;
  const int w = tid >> 6, lane = tid & 63;
  const int wm = w >> 1, wn = w & 1;
  f32x4 acc[4][4];
#pragma unroll
  for (int i = 0; i < 4; i++)
#pragma unroll
    for (int j = 0; j < 4; j++) acc[i][j] = (f32x4){0.f,0.f,0.f,0.f};

  const int srow = tid >> 1;
  const int skseg = (tid & 1) << 4;
  const float* xp = X + (size_t)(m0 + srow) * NK + skseg;
  const u16*  wp  = W1 + (size_t)(n0 + srow) * NK + skseg;

  const int klane = (lane >> 4) << 3;
  const int rowa = wm*64 + (lane & 15);
  const int rowb = wn*64 + (lane & 15);

  for (int k0 = 0; k0 < NK; k0 += 32) {
    __syncthreads();
    f32x4 v0 = *(const f32x4*)(xp + k0 + 0);
    f32x4 v1 = *(const f32x4*)(xp + k0 + 4);
    f32x4 v2 = *(const f32x4*)(xp + k0 + 8);
    f32x4 v3 = *(const f32x4*)(xp + k0 + 12);
    u32x4 q0 = *(const u32x4*)(wp + k0);
    u32x4 q1 = *(const u32x4*)(wp + k0 + 8);
    u32x4 p0, p1;
    p0[0] = pack2(v0[0], v0[1]); p0[1] = pack2(v0[2], v0[3]);
    p0[2] = pack2(v1[0], v1[1]); p0[3] = pack2(v1[2], v1[3]);
    p1[0] = pack2(v2[0], v2[1]); p1[1] = pack2(v2[2], v2[3]);
    p1[2] = pack2(v3[0], v3[1]); p1[3] = pack2(v3[2], v3[3]);
    *(u32x4*)&Alds[srow][skseg]     = p0;
    *(u32x4*)&Alds[srow][skseg + 8] = p1;
    *(u32x4*)&Blds[srow][skseg]     = q0;
    *(u32x4*)&Blds[srow][skseg + 8] = q1;
    __syncthreads();
    bf16x8 af[4], bv[4];
#pragma unroll
    for (int i = 0; i < 4; i++){
      af[i] = *(const bf16x8*)&Alds[rowa + i*16][klane];
      bv[i] = *(const bf16x8*)&Blds[rowb + i*16][klane];
    }
#pragma unroll
    for (int i = 0; i < 4; i++)
#pragma unroll
      for (int j = 0; j < 4; j++)
        acc[i][j] = __builtin_amdgcn_mfma_f32_16x16x32_bf16(af[i], bv[j], acc[i][j], 0, 0, 0);
  }

  const int r0 = (lane >> 4) << 2;
  const int col = lane & 15;
#pragma unroll
  for (int i = 0; i < 4; i++){
    int gm = m0 + wm*64 + i*16 + r0;
#pragma unroll
    for (int j = 0; j < 4; j++){
      int gn = n0 + wn*64 + j*16 + col;
#pragma unroll
      for (int r = 0; r < 4; r++)
        Bu[(size_t)(gm + r) * NN + gn] = f2bf(acc[i][j][r]);
    }
  }
}

// ---------------- scan kernels (verified rounds 2-12) ----------------

__global__ __launch_bounds__(512) void scan_carry(const u16* __restrict__ Bu,
                                                  const float* __restrict__ lam,
                                                  float* __restrict__ carry){
  const int h = threadIdx.x;
  const int bc = blockIdx.x;
  const int b = bc / NCHUNK, c = bc % NCHUNK;
  const float lre = lam[h], lim = lam[NH + h];
  float hre = 0.f, him = 0.f;
  size_t base = (size_t)(b * NL + c * CH) * NN;
  for (int j = 0; j < CH; j++){
    float bre = bf2f(Bu[base + (size_t)j*NN + h]);
    float bim = bf2f(Bu[base + (size_t)j*NN + NH + h]);
    float nre = lre*hre - lim*him + bre;
    float nim = lre*him + lim*hre + bim;
    hre = nre; him = nim;
  }
  size_t ci = ((size_t)bc * NH + h) * 2;
  carry[ci] = hre; carry[ci + 1] = him;
}

__global__ __launch_bounds__(512) void scan_combine(const float* __restrict__ carry,
                                                    const float* __restrict__ lam,
                                                    float* __restrict__ hstart){
  const int h = threadIdx.x;
  const int b = blockIdx.x;
  const float Pre = lam[2*NH + h], Pim = lam[3*NH + h];
  float are = 0.f, aim = 0.f;
  for (int c = 0; c < NCHUNK; c++){
    size_t idx = ((size_t)(b * NCHUNK + c) * NH + h) * 2;
    hstart[idx] = are; hstart[idx + 1] = aim;
    float cre = carry[idx], cim = carry[idx + 1];
    float nre = Pre*are - Pim*aim + cre;
    float nim = Pre*aim + Pim*are + cim;
    are = nre; aim = nim;
  }
}

__global__ __launch_bounds__(512) void scan_fixup_full(u16* __restrict__ Bu,
                                                       const float* __restrict__ lam,
                                                       const float* __restrict__ hstart,
                                                       float* __restrict__ out, int out_size){
  const int h = threadIdx.x;
  const int bc = blockIdx.x;
  const int b = bc / NCHUNK, c = bc % NCHUNK;
  const float lre = lam[h], lim = lam[NH + h];
  size_t si = ((size_t)bc * NH + h) * 2;
  const float sre = hstart[si], sim = hstart[si + 1];
  float hre = 0.f, him = 0.f;
  float pre = lre, pim = lim;
  size_t base = (size_t)(b * NL + c * CH) * NN;
  for (int j = 0; j < CH; j++){
    float bre = bf2f(Bu[base + (size_t)j*NN + h]);
    float bim = bf2f(Bu[base + (size_t)j*NN + NH + h]);
    float nre = lre*hre - lim*him + bre;
    float nim = lre*him + lim*hre + bim;
    hre = nre; him = nim;
    float vre = hre + pre*sre - pim*sim;
    float vim = him + pre*sim + pim*sre;
    Bu[base + (size_t)j*NN + h]      = f2bf(vre);
    Bu[base + (size_t)j*NN + NH + h] = f2bf(vim);
    if (c == NCHUNK - 1 && j == CH - 1){
      size_t ore_i = YCOUNT + (size_t)b * NH + h;
      size_t oim_i = YCOUNT + HCOUNT + (size_t)b * NH + h;
      if (ore_i < (size_t)out_size) out[ore_i] = vre;
      if (oim_i < (size_t)out_size) out[oim_i] = vim;
    }
    float qre = pre*lre - pim*lim;
    float qim = pre*lim + pim*lre;
    pre = qre; pim = qim;
  }
}

// ---------------- launch ----------------

extern "C" void kernel_launch(void* const* d_in, const int* in_sizes, int n_in,
                              void* d_out, int out_size, void* d_ws, size_t ws_size,
                              hipStream_t stream) {
  const float* x         = (const float*)d_in[0];
  const float* theta_log = (const float*)d_in[1];
  const float* nu_log    = (const float*)d_in[2];
  const float* gamma_log = (const float*)d_in[3];
  const float* Bre       = (const float*)d_in[4];
  const float* Bim       = (const float*)d_in[5];
  const float* Cre       = (const float*)d_in[6];
  const float* Cim       = (const float*)d_in[7];
  const float* Dv        = (const float*)d_in[8];
  float* out = (float*)d_out;
  char* ws = (char*)d_ws;

  // workspace layout
  u16*   W1     = (u16*)(ws);                        // 2 MiB
  u16*   W2     = (u16*)(ws + (2u << 20));           // 2 MiB
  float* lam    = (float*)(ws + (4u << 20));         // 8 KiB
  float* carry  = (float*)(ws + (5u << 20));         // 2 MiB
  float* hstart = (float*)(ws + (7u << 20));         // 2 MiB
  u16*   Bu     = (u16*)(ws + (16u << 20));          // 128 MiB
  u16*   Xb     = (u16*)(ws + (144u << 20));         // 128 MiB (fast path only)
  size_t need_base = (16u << 20) + (size_t)NM * NN * 2;           // 144 MiB
  size_t need_fast = need_base + (size_t)NM * NK * 2;             // 272 MiB
  if (ws_size < need_base) return;
  const bool fast = (ws_size >= need_fast);

  prep_w1<<<(NH * NDO + 255) / 256, 256, 0, stream>>>(Bre, Bim, gamma_log, W1);
  prep_w2<<<(NDO * NH + 255) / 256, 256, 0, stream>>>(Cre, Cim, W2);
  prep_lam<<<1, 512, 0, stream>>>(theta_log, nu_log, lam);

  const int g256 = (NM / 256) * (NN / 256);   // 1024 blocks

  if (fast) {
    convert_x<<<(int)(YCOUNT / (256*8)), 256, 0, stream>>>(x, Xb);
    // Final 256x256 probe: amdgpu_waves_per_eu(2,2) pins VGPR budget at 256.
    gemm_256<0><<<g256, 512, 0, stream>>>(Xb, W1, nullptr, nullptr, nullptr, Bu, nullptr);
  } else {
    gemm1_legacy<<<4096, 256, 0, stream>>>(x, W1, Bu);
  }

  scan_carry<<<NB * NCHUNK, 512, 0, stream>>>(Bu, lam, carry);
  scan_combine<<<NB, 512, 0, stream>>>(carry, lam, hstart);
  scan_fixup_full<<<NB * NCHUNK, 512, 0, stream>>>(Bu, lam, hstart, out, out_size);

  if (fast) {
    gemm_sz<2><<<4096, 256, 0, stream>>>(Bu, W2, nullptr, Xb, Dv, nullptr, out);
  } else {
    gemm_sz<1><<<4096, 256, 0, stream>>>(Bu, W2, x, nullptr, Dv, nullptr, out);
  }
}

// Round 19
// 557.315 us; speedup vs baseline: 1.5300x; 1.5279x over previous
//
#include <hip/hip_runtime.h>

#define NB 16
#define NL 4096
#define NDO 1024
#define NH 512
#define NM (NB*NL)          // 65536 rows
#define NK 1024             // K for both GEMMs
#define NN 1024             // N for both GEMMs
#define CH 128
#define NCHUNK (NL/CH)      // 32
#define YCOUNT ((size_t)NM*NDO)   // 67108864
#define HCOUNT ((size_t)NB*NH)    // 8192

typedef unsigned short u16;
typedef float f32x4 __attribute__((ext_vector_type(4)));
typedef unsigned int u32x4 __attribute__((ext_vector_type(4)));
typedef __bf16 bf16x8 __attribute__((ext_vector_type(8)));

__device__ __forceinline__ u16 f2bf(float f){
  unsigned u = __float_as_uint(f);
  unsigned r = u + 0x7fffu + ((u >> 16) & 1u);   // round-to-nearest-even
  return (u16)(r >> 16);
}
__device__ __forceinline__ float bf2f(u16 v){ return __uint_as_float(((unsigned)v) << 16); }
__device__ __forceinline__ unsigned pack2(float a, float b){
  return (unsigned)f2bf(a) | ((unsigned)f2bf(b) << 16);
}

// async global->LDS, 16B per lane; LDS dest = wave-uniform base + lane*16
__device__ __forceinline__ void gld_lds16(const u16* g, u16* l){
  __builtin_amdgcn_global_load_lds(
      (const __attribute__((address_space(1))) unsigned int*)g,
      (__attribute__((address_space(3))) unsigned int*)l,
      16, 0, 0);
}

// ---------------- prep kernels ----------------

__global__ void prep_w1(const float* __restrict__ Bre, const float* __restrict__ Bim,
                        const float* __restrict__ gl, u16* __restrict__ W1){
  int i = blockIdx.x * blockDim.x + threadIdx.x;
  if (i >= NH * NDO) return;
  int h = i / NDO, d = i % NDO;
  float g = expf(gl[h]);
  W1[(size_t)h * NK + d]        = f2bf(Bre[i] * g);
  W1[(size_t)(NH + h) * NK + d] = f2bf(Bim[i] * g);
}

__global__ void prep_w2(const float* __restrict__ Cre, const float* __restrict__ Cim,
                        u16* __restrict__ W2){
  int i = blockIdx.x * blockDim.x + threadIdx.x;
  if (i >= NDO * NH) return;
  int o = i / NH, k = i % NH;
  W2[(size_t)o * NK + k]      = f2bf(Cre[i]);
  W2[(size_t)o * NK + NH + k] = f2bf(-Cim[i]);
}

__global__ void prep_lam(const float* __restrict__ theta_log, const float* __restrict__ nu_log,
                         float* __restrict__ lam){
  int h = threadIdx.x;
  if (h >= NH) return;
  float nu = expf(nu_log[h]);
  float th = expf(theta_log[h]);
  float mag = expf(-nu);
  float lre = mag * cosf(th), lim = mag * sinf(th);
  double pre = (double)lre, pim = (double)lim;
  #pragma unroll
  for (int s = 0; s < 7; s++){
    double nr = pre*pre - pim*pim;
    double ni = 2.0*pre*pim;
    pre = nr; pim = ni;
  }
  lam[h]        = lre;
  lam[NH + h]   = lim;
  lam[2*NH + h] = (float)pre;
  lam[3*NH + h] = (float)pim;
}

// X f32 -> Xb bf16, 8 elements/thread
__global__ __launch_bounds__(256) void convert_x(const float* __restrict__ X, u16* __restrict__ Xb){
  size_t i = ((size_t)blockIdx.x * 256 + threadIdx.x) * 8;
  f32x4 a = *(const f32x4*)(X + i);
  f32x4 b = *(const f32x4*)(X + i + 4);
  u32x4 p;
  p[0] = pack2(a[0], a[1]); p[1] = pack2(a[2], a[3]);
  p[2] = pack2(b[0], b[1]); p[3] = pack2(b[2], b[3]);
  *(u32x4*)(Xb + i) = p;
}

// ==== swizzled 128x128 GEMM: BK=64, [128][64] LDS (128B rows), granule-XOR swizzle ====
// VERIFIED OPTIMUM (rounds 11-15): ~223 us/GEMM, SQ_LDS_BANK_CONFLICT = 0,
// absmax 0.0625. Bank math: row stride 128B -> bank depends only on the 16B
// granule; physical granule = logical ^ (row&7) -> <=2-way conflict (free).
// Staging pre-swizzles the GLOBAL source granule (LDS dest linear, as
// global_load_lds requires); ds_read applies the same XOR (compile-time/lane).
// Pipeline: 2-stage counted vmcnt(8); every buffer overwrite preceded by
// lgkm0+bar of its readers (round-6 race lesson).
// MODE 0: out = bf16 Bu.  MODE 1: f32 Y = acc + Dv*X(f32).  MODE 2: f32 Y = acc + Dv*Xb(bf16).

#define STG_PAIR(AT, BT, t) do {                                 \
    _Pragma("unroll")                                            \
    for (int s = 0; s < 4; s++){                                 \
      gld_lds16(Ag + (size_t)(t)*64 + (size_t)s*8*NK, &AT[w*32 + s*8][0]); \
      gld_lds16(Bg + (size_t)(t)*64 + (size_t)s*8*NK, &BT[w*32 + s*8][0]); \
    }                                                            \
  } while(0)
#define CMP_TILE(AT, BT) do {                                       \
    bf16x8 af[4][2], bv[4][2];                                      \
    _Pragma("unroll")                                               \
    for (int i = 0; i < 4; i++){                                    \
      const u16* pa = &AT[rowa + i*16][0];                          \
      const u16* pb = &BT[rowb + i*16][0];                          \
      af[i][0] = *(const bf16x8*)(pa + sw0);                        \
      af[i][1] = *(const bf16x8*)(pa + sw1);                        \
      bv[i][0] = *(const bf16x8*)(pb + sw0);                        \
      bv[i][1] = *(const bf16x8*)(pb + sw1);                        \
    }                                                               \
    _Pragma("unroll")                                               \
    for (int i = 0; i < 4; i++)                                     \
      _Pragma("unroll")                                             \
      for (int j = 0; j < 4; j++){                                  \
        acc[i][j] = __builtin_amdgcn_mfma_f32_16x16x32_bf16(af[i][0], bv[j][0], acc[i][j], 0, 0, 0); \
        acc[i][j] = __builtin_amdgcn_mfma_f32_16x16x32_bf16(af[i][1], bv[j][1], acc[i][j], 0, 0, 0); \
      }                                                             \
  } while(0)
#define WVM(n)  asm volatile("s_waitcnt vmcnt(" #n ")" ::: "memory")
#define LGKM0() asm volatile("s_waitcnt lgkmcnt(0)" ::: "memory")
#define BARR()  asm volatile("s_barrier" ::: "memory")

template<int MODE>
__global__ __launch_bounds__(256) void gemm_sz(const u16* __restrict__ A,
                                               const u16* __restrict__ W,
                                               const float* __restrict__ Xf,
                                               const u16* __restrict__ Xh,
                                               const float* __restrict__ Dv,
                                               u16* __restrict__ outB,
                                               float* __restrict__ outF){
  __shared__ __align__(16) u16 A0[128][64];   // 16 KiB each; 64 KiB total
  __shared__ __align__(16) u16 B0[128][64];
  __shared__ __align__(16) u16 A1[128][64];
  __shared__ __align__(16) u16 B1[128][64];
  const int tid = threadIdx.x;
  const int bid = blockIdx.x;
  const int lid = (bid & 7) * 512 + (bid >> 3);   // bijective XCD swizzle (4096 = 8*512)
  const int m0 = (lid >> 3) << 7;
  const int n0 = (lid & 7) << 7;
  const int w = tid >> 6, lane = tid & 63;
  const int wm = w >> 1, wn = w & 1;

  // staging: wave w owns rows [w*32, w*32+32); each 1KB DMA = 8 rows x 128B.
  // lane l -> row +(l>>3), physical granule (l&7); source granule pre-swizzled.
  const int grow = lane >> 3;                       // 0..7  (== LDS row & 7)
  const int gcol = ((lane & 7) ^ grow) << 3;        // swizzled source granule (elems)
  const u16* Ag = A + (size_t)(m0 + w*32 + grow) * NK + gcol;
  const u16* Bg = W + (size_t)(n0 + w*32 + grow) * NK + gcol;

  f32x4 acc[4][4];
#pragma unroll
  for (int i = 0; i < 4; i++)
#pragma unroll
    for (int j = 0; j < 4; j++) acc[i][j] = (f32x4){0.f,0.f,0.f,0.f};

  // fragment-read constants: row = base + i*16 + c15; row&7 = lane&7.
  // logical granule = ks*4 + q (q = lane>>4); physical = logical ^ (lane&7).
  const int c15 = lane & 15;
  const int q   = lane >> 4;                        // 0..3
  const int sw0 = ((q    ) ^ (lane & 7)) << 3;      // ks=0 col offset (elems)
  const int sw1 = ((q | 4) ^ (lane & 7)) << 3;      // ks=1
  const int rowa = wm*64 + c15;
  const int rowb = wn*64 + c15;

  // prologue: tiles 0 (P0) and 1 (P1) in flight; wait for tile 0 only
  STG_PAIR(A0, B0, 0);
  STG_PAIR(A1, B1, 1);
  WVM(8);                  // tile 0's 8 loads landed (8 of tile 1 outstanding)
  BARR();

  // 16 K64-tiles; unroll-by-2 keeps all buffer names static (rule #20)
  for (int t = 0; t < 14; t += 2) {
    CMP_TILE(A0, B0);      // tile t
    LGKM0();               // my ds_reads of P0 done
    BARR();                // all waves' reads of P0 done
    STG_PAIR(A0, B0, t + 2);  // refill P0 (outstanding: tile t+1 + tile t+2 = 16)
    WVM(8);                // tile t+1 landed
    BARR();
    CMP_TILE(A1, B1);      // tile t+1
    LGKM0();
    BARR();
    STG_PAIR(A1, B1, t + 3);  // refill P1
    WVM(8);                // tile t+2 landed
    BARR();
  }
  // tail: P0 = tile 14 (landed), P1 = tile 15 (in flight)
  CMP_TILE(A0, B0);
  WVM(0);
  BARR();
  CMP_TILE(A1, B1);

  const int r0 = (lane >> 4) << 2;
#pragma unroll
  for (int i = 0; i < 4; i++){
    int gm = m0 + wm*64 + i*16 + r0;
#pragma unroll
    for (int j = 0; j < 4; j++){
      int gn = n0 + wn*64 + j*16 + c15;
      if constexpr (MODE == 0) {
#pragma unroll
        for (int r = 0; r < 4; r++)
          outB[(size_t)(gm + r) * NN + gn] = f2bf(acc[i][j][r]);
      } else if constexpr (MODE == 1) {
        float dv = Dv[gn];
#pragma unroll
        for (int r = 0; r < 4; r++){
          size_t oidx = (size_t)(gm + r) * NDO + gn;
          outF[oidx] = acc[i][j][r] + dv * Xf[oidx];
        }
      } else {
        float dv = Dv[gn];
#pragma unroll
        for (int r = 0; r < 4; r++){
          size_t oidx = (size_t)(gm + r) * NDO + gn;
          outF[oidx] = acc[i][j][r] + dv * bf2f(Xh[oidx]);
        }
      }
    }
  }
}

// ---------------- legacy GEMM1 (f32 A reg-pack) — fallback if ws too small ----------------

__global__ __launch_bounds__(256) void gemm1_legacy(const float* __restrict__ X,
                                                    const u16* __restrict__ W1,
                                                    u16* __restrict__ Bu){
  __shared__ __align__(16) u16 Alds[128][32];
  __shared__ __align__(16) u16 Blds[128][32];
  const int tid = threadIdx.x;
  const int bid = blockIdx.x;
  const int lid = (bid & 7) * 512 + (bid >> 3);
  const int m0 = (lid >> 3) << 7;
  const int n0 = (lid & 7) << 7;
  const int w = tid >> 6, lane = tid & 63;
  const int wm = w >> 1, wn = w & 1;
  f32x4 acc[4][4];
#pragma unroll
  for (int i = 0; i < 4; i++)
#pragma unroll
    for (int j = 0; j < 4; j++) acc[i][j] = (f32x4){0.f,0.f,0.f,0.f};

  const int srow = tid >> 1;
  const int skseg = (tid & 1) << 4;
  const float* xp = X + (size_t)(m0 + srow) * NK + skseg;
  const u16*  wp  = W1 + (size_t)(n0 + srow) * NK + skseg;

  const int klane = (lane >> 4) << 3;
  const int rowa = wm*64 + (lane & 15);
  const int rowb = wn*64 + (lane & 15);

  for (int k0 = 0; k0 < NK; k0 += 32) {
    __syncthreads();
    f32x4 v0 = *(const f32x4*)(xp + k0 + 0);
    f32x4 v1 = *(const f32x4*)(xp + k0 + 4);
    f32x4 v2 = *(const f32x4*)(xp + k0 + 8);
    f32x4 v3 = *(const f32x4*)(xp + k0 + 12);
    u32x4 q0 = *(const u32x4*)(wp + k0);
    u32x4 q1 = *(const u32x4*)(wp + k0 + 8);
    u32x4 p0, p1;
    p0[0] = pack2(v0[0], v0[1]); p0[1] = pack2(v0[2], v0[3]);
    p0[2] = pack2(v1[0], v1[1]); p0[3] = pack2(v1[2], v1[3]);
    p1[0] = pack2(v2[0], v2[1]); p1[1] = pack2(v2[2], v2[3]);
    p1[2] = pack2(v3[0], v3[1]); p1[3] = pack2(v3[2], v3[3]);
    *(u32x4*)&Alds[srow][skseg]     = p0;
    *(u32x4*)&Alds[srow][skseg + 8] = p1;
    *(u32x4*)&Blds[srow][skseg]     = q0;
    *(u32x4*)&Blds[srow][skseg + 8] = q1;
    __syncthreads();
    bf16x8 af[4], bv[4];
#pragma unroll
    for (int i = 0; i < 4; i++){
      af[i] = *(const bf16x8*)&Alds[rowa + i*16][klane];
      bv[i] = *(const bf16x8*)&Blds[rowb + i*16][klane];
    }
#pragma unroll
    for (int i = 0; i < 4; i++)
#pragma unroll
      for (int j = 0; j < 4; j++)
        acc[i][j] = __builtin_amdgcn_mfma_f32_16x16x32_bf16(af[i], bv[j], acc[i][j], 0, 0, 0);
  }

  const int r0 = (lane >> 4) << 2;
  const int col = lane & 15;
#pragma unroll
  for (int i = 0; i < 4; i++){
    int gm = m0 + wm*64 + i*16 + r0;
#pragma unroll
    for (int j = 0; j < 4; j++){
      int gn = n0 + wn*64 + j*16 + col;
#pragma unroll
      for (int r = 0; r < 4; r++)
        Bu[(size_t)(gm + r) * NN + gn] = f2bf(acc[i][j][r]);
    }
  }
}

// ---------------- scan kernels (verified rounds 2-12) ----------------

__global__ __launch_bounds__(512) void scan_carry(const u16* __restrict__ Bu,
                                                  const float* __restrict__ lam,
                                                  float* __restrict__ carry){
  const int h = threadIdx.x;
  const int bc = blockIdx.x;
  const int b = bc / NCHUNK, c = bc % NCHUNK;
  const float lre = lam[h], lim = lam[NH + h];
  float hre = 0.f, him = 0.f;
  size_t base = (size_t)(b * NL + c * CH) * NN;
  for (int j = 0; j < CH; j++){
    float bre = bf2f(Bu[base + (size_t)j*NN + h]);
    float bim = bf2f(Bu[base + (size_t)j*NN + NH + h]);
    float nre = lre*hre - lim*him + bre;
    float nim = lre*him + lim*hre + bim;
    hre = nre; him = nim;
  }
  size_t ci = ((size_t)bc * NH + h) * 2;
  carry[ci] = hre; carry[ci + 1] = him;
}

__global__ __launch_bounds__(512) void scan_combine(const float* __restrict__ carry,
                                                    const float* __restrict__ lam,
                                                    float* __restrict__ hstart){
  const int h = threadIdx.x;
  const int b = blockIdx.x;
  const float Pre = lam[2*NH + h], Pim = lam[3*NH + h];
  float are = 0.f, aim = 0.f;
  for (int c = 0; c < NCHUNK; c++){
    size_t idx = ((size_t)(b * NCHUNK + c) * NH + h) * 2;
    hstart[idx] = are; hstart[idx + 1] = aim;
    float cre = carry[idx], cim = carry[idx + 1];
    float nre = Pre*are - Pim*aim + cre;
    float nim = Pre*aim + Pim*are + cim;
    are = nre; aim = nim;
  }
}

__global__ __launch_bounds__(512) void scan_fixup_full(u16* __restrict__ Bu,
                                                       const float* __restrict__ lam,
                                                       const float* __restrict__ hstart,
                                                       float* __restrict__ out, int out_size){
  const int h = threadIdx.x;
  const int bc = blockIdx.x;
  const int b = bc / NCHUNK, c = bc % NCHUNK;
  const float lre = lam[h], lim = lam[NH + h];
  size_t si = ((size_t)bc * NH + h) * 2;
  const float sre = hstart[si], sim = hstart[si + 1];
  float hre = 0.f, him = 0.f;
  float pre = lre, pim = lim;
  size_t base = (size_t)(b * NL + c * CH) * NN;
  for (int j = 0; j < CH; j++){
    float bre = bf2f(Bu[base + (size_t)j*NN + h]);
    float bim = bf2f(Bu[base + (size_t)j*NN + NH + h]);
    float nre = lre*hre - lim*him + bre;
    float nim = lre*him + lim*hre + bim;
    hre = nre; him = nim;
    float vre = hre + pre*sre - pim*sim;
    float vim = him + pre*sim + pim*sre;
    Bu[base + (size_t)j*NN + h]      = f2bf(vre);
    Bu[base + (size_t)j*NN + NH + h] = f2bf(vim);
    if (c == NCHUNK - 1 && j == CH - 1){
      size_t ore_i = YCOUNT + (size_t)b * NH + h;
      size_t oim_i = YCOUNT + HCOUNT + (size_t)b * NH + h;
      if (ore_i < (size_t)out_size) out[ore_i] = vre;
      if (oim_i < (size_t)out_size) out[oim_i] = vim;
    }
    float qre = pre*lre - pim*lim;
    float qim = pre*lim + pim*lre;
    pre = qre; pim = qim;
  }
}

// ---------------- launch ----------------

extern "C" void kernel_launch(void* const* d_in, const int* in_sizes, int n_in,
                              void* d_out, int out_size, void* d_ws, size_t ws_size,
                              hipStream_t stream) {
  const float* x         = (const float*)d_in[0];
  const float* theta_log = (const float*)d_in[1];
  const float* nu_log    = (const float*)d_in[2];
  const float* gamma_log = (const float*)d_in[3];
  const float* Bre       = (const float*)d_in[4];
  const float* Bim       = (const float*)d_in[5];
  const float* Cre       = (const float*)d_in[6];
  const float* Cim       = (const float*)d_in[7];
  const float* Dv        = (const float*)d_in[8];
  float* out = (float*)d_out;
  char* ws = (char*)d_ws;

  // workspace layout
  u16*   W1     = (u16*)(ws);                        // 2 MiB
  u16*   W2     = (u16*)(ws + (2u << 20));           // 2 MiB
  float* lam    = (float*)(ws + (4u << 20));         // 8 KiB
  float* carry  = (float*)(ws + (5u << 20));         // 2 MiB
  float* hstart = (float*)(ws + (7u << 20));         // 2 MiB
  u16*   Bu     = (u16*)(ws + (16u << 20));          // 128 MiB
  u16*   Xb     = (u16*)(ws + (144u << 20));         // 128 MiB (fast path only)
  size_t need_base = (16u << 20) + (size_t)NM * NN * 2;           // 144 MiB
  size_t need_fast = need_base + (size_t)NM * NK * 2;             // 272 MiB
  if (ws_size < need_base) return;
  const bool fast = (ws_size >= need_fast);

  prep_w1<<<(NH * NDO + 255) / 256, 256, 0, stream>>>(Bre, Bim, gamma_log, W1);
  prep_w2<<<(NDO * NH + 255) / 256, 256, 0, stream>>>(Cre, Cim, W2);
  prep_lam<<<1, 512, 0, stream>>>(theta_log, nu_log, lam);

  if (fast) {
    convert_x<<<(int)(YCOUNT / (256*8)), 256, 0, stream>>>(x, Xb);
    gemm_sz<0><<<4096, 256, 0, stream>>>(Xb, W1, nullptr, nullptr, nullptr, Bu, nullptr);
  } else {
    gemm1_legacy<<<4096, 256, 0, stream>>>(x, W1, Bu);
  }

  scan_carry<<<NB * NCHUNK, 512, 0, stream>>>(Bu, lam, carry);
  scan_combine<<<NB, 512, 0, stream>>>(carry, lam, hstart);
  scan_fixup_full<<<NB * NCHUNK, 512, 0, stream>>>(Bu, lam, hstart, out, out_size);

  if (fast) {
    gemm_sz<2><<<4096, 256, 0, stream>>>(Bu, W2, nullptr, Xb, Dv, nullptr, out);
  } else {
    gemm_sz<1><<<4096, 256, 0, stream>>>(Bu, W2, x, nullptr, Dv, nullptr, out);
  }
}

// Round 20
// 549.703 us; speedup vs baseline: 1.5511x; 1.0138x over previous
//
#include <hip/hip_runtime.h>

#define NB 16
#define NL 4096
#define NDO 1024
#define NH 512
#define NM (NB*NL)          // 65536 rows
#define NK 1024             // K for both GEMMs
#define NN 1024             // N for both GEMMs
#define CH 128
#define NCHUNK (NL/CH)      // 32
#define YCOUNT ((size_t)NM*NDO)   // 67108864
#define HCOUNT ((size_t)NB*NH)    // 8192

typedef unsigned short u16;
typedef float f32x4 __attribute__((ext_vector_type(4)));
typedef unsigned int u32x4 __attribute__((ext_vector_type(4)));
typedef __bf16 bf16x8 __attribute__((ext_vector_type(8)));

__device__ __forceinline__ u16 f2bf(float f){
  unsigned u = __float_as_uint(f);
  unsigned r = u + 0x7fffu + ((u >> 16) & 1u);   // round-to-nearest-even
  return (u16)(r >> 16);
}
__device__ __forceinline__ float bf2f(u16 v){ return __uint_as_float(((unsigned)v) << 16); }
__device__ __forceinline__ unsigned pack2(float a, float b){
  return (unsigned)f2bf(a) | ((unsigned)f2bf(b) << 16);
}

// async global->LDS, 16B per lane; LDS dest = wave-uniform base + lane*16
__device__ __forceinline__ void gld_lds16(const u16* g, u16* l){
  __builtin_amdgcn_global_load_lds(
      (const __attribute__((address_space(1))) unsigned int*)g,
      (__attribute__((address_space(3))) unsigned int*)l,
      16, 0, 0);
}

// ---------------- prep kernels ----------------

__global__ void prep_w1(const float* __restrict__ Bre, const float* __restrict__ Bim,
                        const float* __restrict__ gl, u16* __restrict__ W1){
  int i = blockIdx.x * blockDim.x + threadIdx.x;
  if (i >= NH * NDO) return;
  int h = i / NDO, d = i % NDO;
  float g = expf(gl[h]);
  W1[(size_t)h * NK + d]        = f2bf(Bre[i] * g);
  W1[(size_t)(NH + h) * NK + d] = f2bf(Bim[i] * g);
}

__global__ void prep_w2(const float* __restrict__ Cre, const float* __restrict__ Cim,
                        u16* __restrict__ W2){
  int i = blockIdx.x * blockDim.x + threadIdx.x;
  if (i >= NDO * NH) return;
  int o = i / NH, k = i % NH;
  W2[(size_t)o * NK + k]      = f2bf(Cre[i]);
  W2[(size_t)o * NK + NH + k] = f2bf(-Cim[i]);
}

__global__ void prep_lam(const float* __restrict__ theta_log, const float* __restrict__ nu_log,
                         float* __restrict__ lam){
  int h = threadIdx.x;
  if (h >= NH) return;
  float nu = expf(nu_log[h]);
  float th = expf(theta_log[h]);
  float mag = expf(-nu);
  float lre = mag * cosf(th), lim = mag * sinf(th);
  double pre = (double)lre, pim = (double)lim;
  #pragma unroll
  for (int s = 0; s < 7; s++){
    double nr = pre*pre - pim*pim;
    double ni = 2.0*pre*pim;
    pre = nr; pim = ni;
  }
  lam[h]        = lre;
  lam[NH + h]   = lim;
  lam[2*NH + h] = (float)pre;
  lam[3*NH + h] = (float)pim;
}

// X f32 -> Xb bf16, 8 elements/thread
__global__ __launch_bounds__(256) void convert_x(const float* __restrict__ X, u16* __restrict__ Xb){
  size_t i = ((size_t)blockIdx.x * 256 + threadIdx.x) * 8;
  f32x4 a = *(const f32x4*)(X + i);
  f32x4 b = *(const f32x4*)(X + i + 4);
  u32x4 p;
  p[0] = pack2(a[0], a[1]); p[1] = pack2(a[2], a[3]);
  p[2] = pack2(b[0], b[1]); p[3] = pack2(b[2], b[3]);
  *(u32x4*)(Xb + i) = p;
}

#define WVM(n)  asm volatile("s_waitcnt vmcnt(" #n ")" ::: "memory")
#define LGKM0() asm volatile("s_waitcnt lgkmcnt(0)" ::: "memory")
#define BARR()  asm volatile("s_barrier" ::: "memory")

// ==== gemm_sz: verified swizzled 128x128 GEMM, 4 waves (rounds 11-19: ~223 us) ====
// MODE 0: out = bf16 Bu.  MODE 1: f32 Y = acc + Dv*X(f32).  MODE 2: f32 Y = acc + Dv*Xb(bf16).

#define STG_PAIR(AT, BT, t) do {                                 \
    _Pragma("unroll")                                            \
    for (int s = 0; s < 4; s++){                                 \
      gld_lds16(Ag + (size_t)(t)*64 + (size_t)s*8*NK, &AT[w*32 + s*8][0]); \
      gld_lds16(Bg + (size_t)(t)*64 + (size_t)s*8*NK, &BT[w*32 + s*8][0]); \
    }                                                            \
  } while(0)
#define CMP_TILE(AT, BT) do {                                       \
    bf16x8 af[4][2], bv[4][2];                                      \
    _Pragma("unroll")                                               \
    for (int i = 0; i < 4; i++){                                    \
      const u16* pa = &AT[rowa + i*16][0];                          \
      const u16* pb = &BT[rowb + i*16][0];                          \
      af[i][0] = *(const bf16x8*)(pa + sw0);                        \
      af[i][1] = *(const bf16x8*)(pa + sw1);                        \
      bv[i][0] = *(const bf16x8*)(pb + sw0);                        \
      bv[i][1] = *(const bf16x8*)(pb + sw1);                        \
    }                                                               \
    _Pragma("unroll")                                               \
    for (int i = 0; i < 4; i++)                                     \
      _Pragma("unroll")                                             \
      for (int j = 0; j < 4; j++){                                  \
        acc[i][j] = __builtin_amdgcn_mfma_f32_16x16x32_bf16(af[i][0], bv[j][0], acc[i][j], 0, 0, 0); \
        acc[i][j] = __builtin_amdgcn_mfma_f32_16x16x32_bf16(af[i][1], bv[j][1], acc[i][j], 0, 0, 0); \
      }                                                             \
  } while(0)

template<int MODE>
__global__ __launch_bounds__(256) void gemm_sz(const u16* __restrict__ A,
                                               const u16* __restrict__ W,
                                               const float* __restrict__ Xf,
                                               const u16* __restrict__ Xh,
                                               const float* __restrict__ Dv,
                                               u16* __restrict__ outB,
                                               float* __restrict__ outF){
  __shared__ __align__(16) u16 A0[128][64];   // 16 KiB each; 64 KiB total
  __shared__ __align__(16) u16 B0[128][64];
  __shared__ __align__(16) u16 A1[128][64];
  __shared__ __align__(16) u16 B1[128][64];
  const int tid = threadIdx.x;
  const int bid = blockIdx.x;
  const int lid = (bid & 7) * 512 + (bid >> 3);   // bijective XCD swizzle (4096 = 8*512)
  const int m0 = (lid >> 3) << 7;
  const int n0 = (lid & 7) << 7;
  const int w = tid >> 6, lane = tid & 63;
  const int wm = w >> 1, wn = w & 1;

  const int grow = lane >> 3;                       // 0..7  (== LDS row & 7)
  const int gcol = ((lane & 7) ^ grow) << 3;        // swizzled source granule (elems)
  const u16* Ag = A + (size_t)(m0 + w*32 + grow) * NK + gcol;
  const u16* Bg = W + (size_t)(n0 + w*32 + grow) * NK + gcol;

  f32x4 acc[4][4];
#pragma unroll
  for (int i = 0; i < 4; i++)
#pragma unroll
    for (int j = 0; j < 4; j++) acc[i][j] = (f32x4){0.f,0.f,0.f,0.f};

  const int c15 = lane & 15;
  const int q   = lane >> 4;
  const int sw0 = ((q    ) ^ (lane & 7)) << 3;
  const int sw1 = ((q | 4) ^ (lane & 7)) << 3;
  const int rowa = wm*64 + c15;
  const int rowb = wn*64 + c15;

  STG_PAIR(A0, B0, 0);
  STG_PAIR(A1, B1, 1);
  WVM(8);
  BARR();
  for (int t = 0; t < 14; t += 2) {
    CMP_TILE(A0, B0);
    LGKM0();
    BARR();
    STG_PAIR(A0, B0, t + 2);
    WVM(8);
    BARR();
    CMP_TILE(A1, B1);
    LGKM0();
    BARR();
    STG_PAIR(A1, B1, t + 3);
    WVM(8);
    BARR();
  }
  CMP_TILE(A0, B0);
  WVM(0);
  BARR();
  CMP_TILE(A1, B1);

  const int r0 = (lane >> 4) << 2;
#pragma unroll
  for (int i = 0; i < 4; i++){
    int gm = m0 + wm*64 + i*16 + r0;
#pragma unroll
    for (int j = 0; j < 4; j++){
      int gn = n0 + wn*64 + j*16 + c15;
      if constexpr (MODE == 0) {
#pragma unroll
        for (int r = 0; r < 4; r++)
          outB[(size_t)(gm + r) * NN + gn] = f2bf(acc[i][j][r]);
      } else if constexpr (MODE == 1) {
        float dv = Dv[gn];
#pragma unroll
        for (int r = 0; r < 4; r++){
          size_t oidx = (size_t)(gm + r) * NDO + gn;
          outF[oidx] = acc[i][j][r] + dv * Xf[oidx];
        }
      } else {
        float dv = Dv[gn];
#pragma unroll
        for (int r = 0; r < 4; r++){
          size_t oidx = (size_t)(gm + r) * NDO + gn;
          outF[oidx] = acc[i][j][r] + dv * bf2f(Xh[oidx]);
        }
      }
    }
  }
}

// ==== gemm_sz8w: SAME tile/swizzle/pipeline, 512 threads / 8 waves ====
// 2 blocks/CU unchanged (64KB LDS) but 4 waves/SIMD instead of 2 -> 2x TLP.
// Wave grid 2x4, per-wave output 64x32 (acc[4][2] = 32 VGPRs, ~100 total).
// Each wave stages 16 A-rows + 16 B-rows per tile = 4 gld_lds16 -> vmcnt(4).
// Swizzle invariant preserved: wave row-bases are multiples of 8 (row&7 == grow).
template<int MODE>
__global__ __launch_bounds__(512) void gemm_sz8w(const u16* __restrict__ A,
                                                 const u16* __restrict__ W,
                                                 const u16* __restrict__ Xh,
                                                 const float* __restrict__ Dv,
                                                 u16* __restrict__ outB,
                                                 float* __restrict__ outF){
  __shared__ __align__(16) u16 A0[128][64];
  __shared__ __align__(16) u16 B0[128][64];
  __shared__ __align__(16) u16 A1[128][64];
  __shared__ __align__(16) u16 B1[128][64];
  const int tid = threadIdx.x;
  const int bid = blockIdx.x;
  const int lid = (bid & 7) * 512 + (bid >> 3);
  const int m0 = (lid >> 3) << 7;
  const int n0 = (lid & 7) << 7;
  const int w = tid >> 6, lane = tid & 63;      // w in [0,8)
  const int wm = w >> 2, wn = w & 3;            // 2 x 4 wave grid

  const int grow = lane >> 3;
  const int gcol = ((lane & 7) ^ grow) << 3;
  const u16* Ag = A + (size_t)(m0 + w*16 + grow) * NK + gcol;   // wave stages rows [w*16, w*16+16)
  const u16* Bg = W + (size_t)(n0 + w*16 + grow) * NK + gcol;

  f32x4 acc[4][2];
#pragma unroll
  for (int i = 0; i < 4; i++)
#pragma unroll
    for (int j = 0; j < 2; j++) acc[i][j] = (f32x4){0.f,0.f,0.f,0.f};

  const int c15 = lane & 15;
  const int q   = lane >> 4;
  const int sw0 = ((q    ) ^ (lane & 7)) << 3;
  const int sw1 = ((q | 4) ^ (lane & 7)) << 3;
  const int rowa = wm*64 + c15;   // 64-row A stripe
  const int rowb = wn*32 + c15;   // 32-row B stripe

#define STG8(AT, BT, t) do {                                             \
    _Pragma("unroll")                                                    \
    for (int s = 0; s < 2; s++){                                         \
      gld_lds16(Ag + (size_t)(t)*64 + (size_t)s*8*NK, &AT[w*16 + s*8][0]); \
      gld_lds16(Bg + (size_t)(t)*64 + (size_t)s*8*NK, &BT[w*16 + s*8][0]); \
    }                                                                    \
  } while(0)
#define CMP8(AT, BT) do {                                           \
    bf16x8 af[4][2], bv[2][2];                                      \
    _Pragma("unroll")                                               \
    for (int i = 0; i < 4; i++){                                    \
      const u16* pa = &AT[rowa + i*16][0];                          \
      af[i][0] = *(const bf16x8*)(pa + sw0);                        \
      af[i][1] = *(const bf16x8*)(pa + sw1);                        \
    }                                                               \
    _Pragma("unroll")                                               \
    for (int j = 0; j < 2; j++){                                    \
      const u16* pb = &BT[rowb + j*16][0];                          \
      bv[j][0] = *(const bf16x8*)(pb + sw0);                        \
      bv[j][1] = *(const bf16x8*)(pb + sw1);                        \
    }                                                               \
    _Pragma("unroll")                                               \
    for (int i = 0; i < 4; i++)                                     \
      _Pragma("unroll")                                             \
      for (int j = 0; j < 2; j++){                                  \
        acc[i][j] = __builtin_amdgcn_mfma_f32_16x16x32_bf16(af[i][0], bv[j][0], acc[i][j], 0, 0, 0); \
        acc[i][j] = __builtin_amdgcn_mfma_f32_16x16x32_bf16(af[i][1], bv[j][1], acc[i][j], 0, 0, 0); \
      }                                                             \
  } while(0)

  STG8(A0, B0, 0);
  STG8(A1, B1, 1);
  WVM(4);                   // tile 0's 4 loads landed (4 of tile 1 outstanding)
  BARR();
  for (int t = 0; t < 14; t += 2) {
    CMP8(A0, B0);           // tile t
    LGKM0();                // my ds_reads of P0 done
    BARR();                 // all waves' reads of P0 done
    STG8(A0, B0, t + 2);    // refill P0 (outstanding: 4 t+1 + 4 t+2)
    WVM(4);                 // tile t+1 landed
    BARR();
    CMP8(A1, B1);           // tile t+1
    LGKM0();
    BARR();
    STG8(A1, B1, t + 3);    // refill P1
    WVM(4);                 // tile t+2 landed
    BARR();
  }
  CMP8(A0, B0);
  WVM(0);
  BARR();
  CMP8(A1, B1);

#undef STG8
#undef CMP8

  const int r0 = (lane >> 4) << 2;
#pragma unroll
  for (int i = 0; i < 4; i++){
    int gm = m0 + wm*64 + i*16 + r0;
#pragma unroll
    for (int j = 0; j < 2; j++){
      int gn = n0 + wn*32 + j*16 + c15;
      if constexpr (MODE == 0) {
#pragma unroll
        for (int r = 0; r < 4; r++)
          outB[(size_t)(gm + r) * NN + gn] = f2bf(acc[i][j][r]);
      } else {
        float dv = Dv[gn];
#pragma unroll
        for (int r = 0; r < 4; r++){
          size_t oidx = (size_t)(gm + r) * NDO + gn;
          outF[oidx] = acc[i][j][r] + dv * bf2f(Xh[oidx]);
        }
      }
    }
  }
}

// ---------------- legacy GEMM1 (f32 A reg-pack) — fallback if ws too small ----------------

__global__ __launch_bounds__(256) void gemm1_legacy(const float* __restrict__ X,
                                                    const u16* __restrict__ W1,
                                                    u16* __restrict__ Bu){
  __shared__ __align__(16) u16 Alds[128][32];
  __shared__ __align__(16) u16 Blds[128][32];
  const int tid = threadIdx.x;
  const int bid = blockIdx.x;
  const int lid = (bid & 7) * 512 + (bid >> 3);
  const int m0 = (lid >> 3) << 7;
  const int n0 = (lid & 7) << 7;
  const int w = tid >> 6, lane = tid & 63;
  const int wm = w >> 1, wn = w & 1;
  f32x4 acc[4][4];
#pragma unroll
  for (int i = 0; i < 4; i++)
#pragma unroll
    for (int j = 0; j < 4; j++) acc[i][j] = (f32x4){0.f,0.f,0.f,0.f};

  const int srow = tid >> 1;
  const int skseg = (tid & 1) << 4;
  const float* xp = X + (size_t)(m0 + srow) * NK + skseg;
  const u16*  wp  = W1 + (size_t)(n0 + srow) * NK + skseg;

  const int klane = (lane >> 4) << 3;
  const int rowa = wm*64 + (lane & 15);
  const int rowb = wn*64 + (lane & 15);

  for (int k0 = 0; k0 < NK; k0 += 32) {
    __syncthreads();
    f32x4 v0 = *(const f32x4*)(xp + k0 + 0);
    f32x4 v1 = *(const f32x4*)(xp + k0 + 4);
    f32x4 v2 = *(const f32x4*)(xp + k0 + 8);
    f32x4 v3 = *(const f32x4*)(xp + k0 + 12);
    u32x4 q0 = *(const u32x4*)(wp + k0);
    u32x4 q1 = *(const u32x4*)(wp + k0 + 8);
    u32x4 p0, p1;
    p0[0] = pack2(v0[0], v0[1]); p0[1] = pack2(v0[2], v0[3]);
    p0[2] = pack2(v1[0], v1[1]); p0[3] = pack2(v1[2], v1[3]);
    p1[0] = pack2(v2[0], v2[1]); p1[1] = pack2(v2[2], v2[3]);
    p1[2] = pack2(v3[0], v3[1]); p1[3] = pack2(v3[2], v3[3]);
    *(u32x4*)&Alds[srow][skseg]     = p0;
    *(u32x4*)&Alds[srow][skseg + 8] = p1;
    *(u32x4*)&Blds[srow][skseg]     = q0;
    *(u32x4*)&Blds[srow][skseg + 8] = q1;
    __syncthreads();
    bf16x8 af[4], bv[4];
#pragma unroll
    for (int i = 0; i < 4; i++){
      af[i] = *(const bf16x8*)&Alds[rowa + i*16][klane];
      bv[i] = *(const bf16x8*)&Blds[rowb + i*16][klane];
    }
#pragma unroll
    for (int i = 0; i < 4; i++)
#pragma unroll
      for (int j = 0; j < 4; j++)
        acc[i][j] = __builtin_amdgcn_mfma_f32_16x16x32_bf16(af[i], bv[j], acc[i][j], 0, 0, 0);
  }

  const int r0 = (lane >> 4) << 2;
  const int col = lane & 15;
#pragma unroll
  for (int i = 0; i < 4; i++){
    int gm = m0 + wm*64 + i*16 + r0;
#pragma unroll
    for (int j = 0; j < 4; j++){
      int gn = n0 + wn*64 + j*16 + col;
#pragma unroll
      for (int r = 0; r < 4; r++)
        Bu[(size_t)(gm + r) * NN + gn] = f2bf(acc[i][j][r]);
    }
  }
}

// ---------------- scan kernels (verified rounds 2-12) ----------------

__global__ __launch_bounds__(512) void scan_carry(const u16* __restrict__ Bu,
                                                  const float* __restrict__ lam,
                                                  float* __restrict__ carry){
  const int h = threadIdx.x;
  const int bc = blockIdx.x;
  const int b = bc / NCHUNK, c = bc % NCHUNK;
  const float lre = lam[h], lim = lam[NH + h];
  float hre = 0.f, him = 0.f;
  size_t base = (size_t)(b * NL + c * CH) * NN;
  for (int j = 0; j < CH; j++){
    float bre = bf2f(Bu[base + (size_t)j*NN + h]);
    float bim = bf2f(Bu[base + (size_t)j*NN + NH + h]);
    float nre = lre*hre - lim*him + bre;
    float nim = lre*him + lim*hre + bim;
    hre = nre; him = nim;
  }
  size_t ci = ((size_t)bc * NH + h) * 2;
  carry[ci] = hre; carry[ci + 1] = him;
}

__global__ __launch_bounds__(512) void scan_combine(const float* __restrict__ carry,
                                                    const float* __restrict__ lam,
                                                    float* __restrict__ hstart){
  const int h = threadIdx.x;
  const int b = blockIdx.x;
  const float Pre = lam[2*NH + h], Pim = lam[3*NH + h];
  float are = 0.f, aim = 0.f;
  for (int c = 0; c < NCHUNK; c++){
    size_t idx = ((size_t)(b * NCHUNK + c) * NH + h) * 2;
    hstart[idx] = are; hstart[idx + 1] = aim;
    float cre = carry[idx], cim = carry[idx + 1];
    float nre = Pre*are - Pim*aim + cre;
    float nim = Pre*aim + Pim*are + cim;
    are = nre; aim = nim;
  }
}

__global__ __launch_bounds__(512) void scan_fixup_full(u16* __restrict__ Bu,
                                                       const float* __restrict__ lam,
                                                       const float* __restrict__ hstart,
                                                       float* __restrict__ out, int out_size){
  const int h = threadIdx.x;
  const int bc = blockIdx.x;
  const int b = bc / NCHUNK, c = bc % NCHUNK;
  const float lre = lam[h], lim = lam[NH + h];
  size_t si = ((size_t)bc * NH + h) * 2;
  const float sre = hstart[si], sim = hstart[si + 1];
  float hre = 0.f, him = 0.f;
  float pre = lre, pim = lim;
  size_t base = (size_t)(b * NL + c * CH) * NN;
  for (int j = 0; j < CH; j++){
    float bre = bf2f(Bu[base + (size_t)j*NN + h]);
    float bim = bf2f(Bu[base + (size_t)j*NN + NH + h]);
    float nre = lre*hre - lim*him + bre;
    float nim = lre*him + lim*hre + bim;
    hre = nre; him = nim;
    float vre = hre + pre*sre - pim*sim;
    float vim = him + pre*sim + pim*sre;
    Bu[base + (size_t)j*NN + h]      = f2bf(vre);
    Bu[base + (size_t)j*NN + NH + h] = f2bf(vim);
    if (c == NCHUNK - 1 && j == CH - 1){
      size_t ore_i = YCOUNT + (size_t)b * NH + h;
      size_t oim_i = YCOUNT + HCOUNT + (size_t)b * NH + h;
      if (ore_i < (size_t)out_size) out[ore_i] = vre;
      if (oim_i < (size_t)out_size) out[oim_i] = vim;
    }
    float qre = pre*lre - pim*lim;
    float qim = pre*lim + pim*lre;
    pre = qre; pim = qim;
  }
}

// ---------------- launch ----------------

extern "C" void kernel_launch(void* const* d_in, const int* in_sizes, int n_in,
                              void* d_out, int out_size, void* d_ws, size_t ws_size,
                              hipStream_t stream) {
  const float* x         = (const float*)d_in[0];
  const float* theta_log = (const float*)d_in[1];
  const float* nu_log    = (const float*)d_in[2];
  const float* gamma_log = (const float*)d_in[3];
  const float* Bre       = (const float*)d_in[4];
  const float* Bim       = (const float*)d_in[5];
  const float* Cre       = (const float*)d_in[6];
  const float* Cim       = (const float*)d_in[7];
  const float* Dv        = (const float*)d_in[8];
  float* out = (float*)d_out;
  char* ws = (char*)d_ws;

  // workspace layout
  u16*   W1     = (u16*)(ws);                        // 2 MiB
  u16*   W2     = (u16*)(ws + (2u << 20));           // 2 MiB
  float* lam    = (float*)(ws + (4u << 20));         // 8 KiB
  float* carry  = (float*)(ws + (5u << 20));         // 2 MiB
  float* hstart = (float*)(ws + (7u << 20));         // 2 MiB
  u16*   Bu     = (u16*)(ws + (16u << 20));          // 128 MiB
  u16*   Xb     = (u16*)(ws + (144u << 20));         // 128 MiB (fast path only)
  size_t need_base = (16u << 20) + (size_t)NM * NN * 2;           // 144 MiB
  size_t need_fast = need_base + (size_t)NM * NK * 2;             // 272 MiB
  if (ws_size < need_base) return;
  const bool fast = (ws_size >= need_fast);

  prep_w1<<<(NH * NDO + 255) / 256, 256, 0, stream>>>(Bre, Bim, gamma_log, W1);
  prep_w2<<<(NDO * NH + 255) / 256, 256, 0, stream>>>(Cre, Cim, W2);
  prep_lam<<<1, 512, 0, stream>>>(theta_log, nu_log, lam);

  if (fast) {
    convert_x<<<(int)(YCOUNT / (256*8)), 256, 0, stream>>>(x, Xb);
    // A/B probe: gemm1 = 8-wave variant (4 waves/SIMD); gemm2 = 4-wave control
    gemm_sz8w<0><<<4096, 512, 0, stream>>>(Xb, W1, nullptr, nullptr, Bu, nullptr);
  } else {
    gemm1_legacy<<<4096, 256, 0, stream>>>(x, W1, Bu);
  }

  scan_carry<<<NB * NCHUNK, 512, 0, stream>>>(Bu, lam, carry);
  scan_combine<<<NB, 512, 0, stream>>>(carry, lam, hstart);
  scan_fixup_full<<<NB * NCHUNK, 512, 0, stream>>>(Bu, lam, hstart, out, out_size);

  if (fast) {
    gemm_sz<2><<<4096, 256, 0, stream>>>(Bu, W2, nullptr, Xb, Dv, nullptr, out);
  } else {
    gemm_sz<1><<<4096, 256, 0, stream>>>(Bu, W2, x, nullptr, Dv, nullptr, out);
  }
}

// Round 21
// 547.994 us; speedup vs baseline: 1.5560x; 1.0031x over previous
//
#include <hip/hip_runtime.h>

#define NB 16
#define NL 4096
#define NDO 1024
#define NH 512
#define NM (NB*NL)          // 65536 rows
#define NK 1024             // K for both GEMMs
#define NN 1024             // N for both GEMMs
#define CH 128
#define NCHUNK (NL/CH)      // 32
#define YCOUNT ((size_t)NM*NDO)   // 67108864
#define HCOUNT ((size_t)NB*NH)    // 8192

typedef unsigned short u16;
typedef float f32x4 __attribute__((ext_vector_type(4)));
typedef unsigned int u32x4 __attribute__((ext_vector_type(4)));
typedef __bf16 bf16x8 __attribute__((ext_vector_type(8)));

__device__ __forceinline__ u16 f2bf(float f){
  unsigned u = __float_as_uint(f);
  unsigned r = u + 0x7fffu + ((u >> 16) & 1u);   // round-to-nearest-even
  return (u16)(r >> 16);
}
__device__ __forceinline__ float bf2f(u16 v){ return __uint_as_float(((unsigned)v) << 16); }
__device__ __forceinline__ unsigned pack2(float a, float b){
  return (unsigned)f2bf(a) | ((unsigned)f2bf(b) << 16);
}

// async global->LDS, 16B per lane; LDS dest = wave-uniform base + lane*16
__device__ __forceinline__ void gld_lds16(const u16* g, u16* l){
  __builtin_amdgcn_global_load_lds(
      (const __attribute__((address_space(1))) unsigned int*)g,
      (__attribute__((address_space(3))) unsigned int*)l,
      16, 0, 0);
}

// ---------------- prep kernels ----------------

__global__ void prep_w1(const float* __restrict__ Bre, const float* __restrict__ Bim,
                        const float* __restrict__ gl, u16* __restrict__ W1){
  int i = blockIdx.x * blockDim.x + threadIdx.x;
  if (i >= NH * NDO) return;
  int h = i / NDO, d = i % NDO;
  float g = expf(gl[h]);
  W1[(size_t)h * NK + d]        = f2bf(Bre[i] * g);
  W1[(size_t)(NH + h) * NK + d] = f2bf(Bim[i] * g);
}

__global__ void prep_w2(const float* __restrict__ Cre, const float* __restrict__ Cim,
                        u16* __restrict__ W2){
  int i = blockIdx.x * blockDim.x + threadIdx.x;
  if (i >= NDO * NH) return;
  int o = i / NH, k = i % NH;
  W2[(size_t)o * NK + k]      = f2bf(Cre[i]);
  W2[(size_t)o * NK + NH + k] = f2bf(-Cim[i]);
}

__global__ void prep_lam(const float* __restrict__ theta_log, const float* __restrict__ nu_log,
                         float* __restrict__ lam){
  int h = threadIdx.x;
  if (h >= NH) return;
  float nu = expf(nu_log[h]);
  float th = expf(theta_log[h]);
  float mag = expf(-nu);
  float lre = mag * cosf(th), lim = mag * sinf(th);
  double pre = (double)lre, pim = (double)lim;
  #pragma unroll
  for (int s = 0; s < 7; s++){
    double nr = pre*pre - pim*pim;
    double ni = 2.0*pre*pim;
    pre = nr; pim = ni;
  }
  lam[h]        = lre;
  lam[NH + h]   = lim;
  lam[2*NH + h] = (float)pre;
  lam[3*NH + h] = (float)pim;
}

// X f32 -> Xb bf16, 8 elements/thread
__global__ __launch_bounds__(256) void convert_x(const float* __restrict__ X, u16* __restrict__ Xb){
  size_t i = ((size_t)blockIdx.x * 256 + threadIdx.x) * 8;
  f32x4 a = *(const f32x4*)(X + i);
  f32x4 b = *(const f32x4*)(X + i + 4);
  u32x4 p;
  p[0] = pack2(a[0], a[1]); p[1] = pack2(a[2], a[3]);
  p[2] = pack2(b[0], b[1]); p[3] = pack2(b[2], b[3]);
  *(u32x4*)(Xb + i) = p;
}

#define WVM(n)  asm volatile("s_waitcnt vmcnt(" #n ")" ::: "memory")
#define LGKM0() asm volatile("s_waitcnt lgkmcnt(0)" ::: "memory")
#define BARR()  asm volatile("s_barrier" ::: "memory")

// ==== gemm_sz: verified swizzled 128x128 GEMM, 4 waves (fallback path only) ====
// MODE 1: f32 Y = acc + Dv*X(f32).

#define STG_PAIR(AT, BT, t) do {                                 \
    _Pragma("unroll")                                            \
    for (int s = 0; s < 4; s++){                                 \
      gld_lds16(Ag + (size_t)(t)*64 + (size_t)s*8*NK, &AT[w*32 + s*8][0]); \
      gld_lds16(Bg + (size_t)(t)*64 + (size_t)s*8*NK, &BT[w*32 + s*8][0]); \
    }                                                            \
  } while(0)
#define CMP_TILE(AT, BT) do {                                       \
    bf16x8 af[4][2], bv[4][2];                                      \
    _Pragma("unroll")                                               \
    for (int i = 0; i < 4; i++){                                    \
      const u16* pa = &AT[rowa + i*16][0];                          \
      const u16* pb = &BT[rowb + i*16][0];                          \
      af[i][0] = *(const bf16x8*)(pa + sw0);                        \
      af[i][1] = *(const bf16x8*)(pa + sw1);                        \
      bv[i][0] = *(const bf16x8*)(pb + sw0);                        \
      bv[i][1] = *(const bf16x8*)(pb + sw1);                        \
    }                                                               \
    _Pragma("unroll")                                               \
    for (int i = 0; i < 4; i++)                                     \
      _Pragma("unroll")                                             \
      for (int j = 0; j < 4; j++){                                  \
        acc[i][j] = __builtin_amdgcn_mfma_f32_16x16x32_bf16(af[i][0], bv[j][0], acc[i][j], 0, 0, 0); \
        acc[i][j] = __builtin_amdgcn_mfma_f32_16x16x32_bf16(af[i][1], bv[j][1], acc[i][j], 0, 0, 0); \
      }                                                             \
  } while(0)

template<int MODE>
__global__ __launch_bounds__(256) void gemm_sz(const u16* __restrict__ A,
                                               const u16* __restrict__ W,
                                               const float* __restrict__ Xf,
                                               const u16* __restrict__ Xh,
                                               const float* __restrict__ Dv,
                                               u16* __restrict__ outB,
                                               float* __restrict__ outF){
  __shared__ __align__(16) u16 A0[128][64];   // 16 KiB each; 64 KiB total
  __shared__ __align__(16) u16 B0[128][64];
  __shared__ __align__(16) u16 A1[128][64];
  __shared__ __align__(16) u16 B1[128][64];
  const int tid = threadIdx.x;
  const int bid = blockIdx.x;
  const int lid = (bid & 7) * 512 + (bid >> 3);   // bijective XCD swizzle (4096 = 8*512)
  const int m0 = (lid >> 3) << 7;
  const int n0 = (lid & 7) << 7;
  const int w = tid >> 6, lane = tid & 63;
  const int wm = w >> 1, wn = w & 1;

  const int grow = lane >> 3;                       // 0..7  (== LDS row & 7)
  const int gcol = ((lane & 7) ^ grow) << 3;        // swizzled source granule (elems)
  const u16* Ag = A + (size_t)(m0 + w*32 + grow) * NK + gcol;
  const u16* Bg = W + (size_t)(n0 + w*32 + grow) * NK + gcol;

  f32x4 acc[4][4];
#pragma unroll
  for (int i = 0; i < 4; i++)
#pragma unroll
    for (int j = 0; j < 4; j++) acc[i][j] = (f32x4){0.f,0.f,0.f,0.f};

  const int c15 = lane & 15;
  const int q   = lane >> 4;
  const int sw0 = ((q    ) ^ (lane & 7)) << 3;
  const int sw1 = ((q | 4) ^ (lane & 7)) << 3;
  const int rowa = wm*64 + c15;
  const int rowb = wn*64 + c15;

  STG_PAIR(A0, B0, 0);
  STG_PAIR(A1, B1, 1);
  WVM(8);
  BARR();
  for (int t = 0; t < 14; t += 2) {
    CMP_TILE(A0, B0);
    LGKM0();
    BARR();
    STG_PAIR(A0, B0, t + 2);
    WVM(8);
    BARR();
    CMP_TILE(A1, B1);
    LGKM0();
    BARR();
    STG_PAIR(A1, B1, t + 3);
    WVM(8);
    BARR();
  }
  CMP_TILE(A0, B0);
  WVM(0);
  BARR();
  CMP_TILE(A1, B1);

  const int r0 = (lane >> 4) << 2;
#pragma unroll
  for (int i = 0; i < 4; i++){
    int gm = m0 + wm*64 + i*16 + r0;
#pragma unroll
    for (int j = 0; j < 4; j++){
      int gn = n0 + wn*64 + j*16 + c15;
      if constexpr (MODE == 0) {
#pragma unroll
        for (int r = 0; r < 4; r++)
          outB[(size_t)(gm + r) * NN + gn] = f2bf(acc[i][j][r]);
      } else if constexpr (MODE == 1) {
        float dv = Dv[gn];
#pragma unroll
        for (int r = 0; r < 4; r++){
          size_t oidx = (size_t)(gm + r) * NDO + gn;
          outF[oidx] = acc[i][j][r] + dv * Xf[oidx];
        }
      } else {
        float dv = Dv[gn];
#pragma unroll
        for (int r = 0; r < 4; r++){
          size_t oidx = (size_t)(gm + r) * NDO + gn;
          outF[oidx] = acc[i][j][r] + dv * bf2f(Xh[oidx]);
        }
      }
    }
  }
}

// ==== gemm_sz8w: PROMOTED winner — same tile/swizzle/pipeline, 512 threads / 8 waves ====
// Round-20 A/B verified: ~216 us vs 224 us 4-wave control (4 waves/SIMD doubles TLP).
// Wave grid 2x4, per-wave output 64x32 (acc[4][2]); each wave stages 16 A-rows +
// 16 B-rows per tile = 4 gld_lds16 -> vmcnt(4). Swizzle invariant preserved
// (wave row-bases are multiples of 8 -> row&7 == grow).
// MODE 0: out = bf16 Bu.  MODE 2: f32 Y = acc + Dv*Xb(bf16).
template<int MODE>
__global__ __launch_bounds__(512) void gemm_sz8w(const u16* __restrict__ A,
                                                 const u16* __restrict__ W,
                                                 const u16* __restrict__ Xh,
                                                 const float* __restrict__ Dv,
                                                 u16* __restrict__ outB,
                                                 float* __restrict__ outF){
  __shared__ __align__(16) u16 A0[128][64];
  __shared__ __align__(16) u16 B0[128][64];
  __shared__ __align__(16) u16 A1[128][64];
  __shared__ __align__(16) u16 B1[128][64];
  const int tid = threadIdx.x;
  const int bid = blockIdx.x;
  const int lid = (bid & 7) * 512 + (bid >> 3);
  const int m0 = (lid >> 3) << 7;
  const int n0 = (lid & 7) << 7;
  const int w = tid >> 6, lane = tid & 63;      // w in [0,8)
  const int wm = w >> 2, wn = w & 3;            // 2 x 4 wave grid

  const int grow = lane >> 3;
  const int gcol = ((lane & 7) ^ grow) << 3;
  const u16* Ag = A + (size_t)(m0 + w*16 + grow) * NK + gcol;   // wave stages rows [w*16, w*16+16)
  const u16* Bg = W + (size_t)(n0 + w*16 + grow) * NK + gcol;

  f32x4 acc[4][2];
#pragma unroll
  for (int i = 0; i < 4; i++)
#pragma unroll
    for (int j = 0; j < 2; j++) acc[i][j] = (f32x4){0.f,0.f,0.f,0.f};

  const int c15 = lane & 15;
  const int q   = lane >> 4;
  const int sw0 = ((q    ) ^ (lane & 7)) << 3;
  const int sw1 = ((q | 4) ^ (lane & 7)) << 3;
  const int rowa = wm*64 + c15;   // 64-row A stripe
  const int rowb = wn*32 + c15;   // 32-row B stripe

#define STG8(AT, BT, t) do {                                             \
    _Pragma("unroll")                                                    \
    for (int s = 0; s < 2; s++){                                         \
      gld_lds16(Ag + (size_t)(t)*64 + (size_t)s*8*NK, &AT[w*16 + s*8][0]); \
      gld_lds16(Bg + (size_t)(t)*64 + (size_t)s*8*NK, &BT[w*16 + s*8][0]); \
    }                                                                    \
  } while(0)
#define CMP8(AT, BT) do {                                           \
    bf16x8 af[4][2], bv[2][2];                                      \
    _Pragma("unroll")                                               \
    for (int i = 0; i < 4; i++){                                    \
      const u16* pa = &AT[rowa + i*16][0];                          \
      af[i][0] = *(const bf16x8*)(pa + sw0);                        \
      af[i][1] = *(const bf16x8*)(pa + sw1);                        \
    }                                                               \
    _Pragma("unroll")                                               \
    for (int j = 0; j < 2; j++){                                    \
      const u16* pb = &BT[rowb + j*16][0];                          \
      bv[j][0] = *(const bf16x8*)(pb + sw0);                        \
      bv[j][1] = *(const bf16x8*)(pb + sw1);                        \
    }                                                               \
    _Pragma("unroll")                                               \
    for (int i = 0; i < 4; i++)                                     \
      _Pragma("unroll")                                             \
      for (int j = 0; j < 2; j++){                                  \
        acc[i][j] = __builtin_amdgcn_mfma_f32_16x16x32_bf16(af[i][0], bv[j][0], acc[i][j], 0, 0, 0); \
        acc[i][j] = __builtin_amdgcn_mfma_f32_16x16x32_bf16(af[i][1], bv[j][1], acc[i][j], 0, 0, 0); \
      }                                                             \
  } while(0)

  STG8(A0, B0, 0);
  STG8(A1, B1, 1);
  WVM(4);                   // tile 0's 4 loads landed (4 of tile 1 outstanding)
  BARR();
  for (int t = 0; t < 14; t += 2) {
    CMP8(A0, B0);           // tile t
    LGKM0();                // my ds_reads of P0 done
    BARR();                 // all waves' reads of P0 done
    STG8(A0, B0, t + 2);    // refill P0 (outstanding: 4 t+1 + 4 t+2)
    WVM(4);                 // tile t+1 landed
    BARR();
    CMP8(A1, B1);           // tile t+1
    LGKM0();
    BARR();
    STG8(A1, B1, t + 3);    // refill P1
    WVM(4);                 // tile t+2 landed
    BARR();
  }
  CMP8(A0, B0);
  WVM(0);
  BARR();
  CMP8(A1, B1);

#undef STG8
#undef CMP8

  const int r0 = (lane >> 4) << 2;
#pragma unroll
  for (int i = 0; i < 4; i++){
    int gm = m0 + wm*64 + i*16 + r0;
#pragma unroll
    for (int j = 0; j < 2; j++){
      int gn = n0 + wn*32 + j*16 + c15;
      if constexpr (MODE == 0) {
#pragma unroll
        for (int r = 0; r < 4; r++)
          outB[(size_t)(gm + r) * NN + gn] = f2bf(acc[i][j][r]);
      } else {
        float dv = Dv[gn];
#pragma unroll
        for (int r = 0; r < 4; r++){
          size_t oidx = (size_t)(gm + r) * NDO + gn;
          outF[oidx] = acc[i][j][r] + dv * bf2f(Xh[oidx]);
        }
      }
    }
  }
}

// ---------------- legacy GEMM1 (f32 A reg-pack) — fallback if ws too small ----------------

__global__ __launch_bounds__(256) void gemm1_legacy(const float* __restrict__ X,
                                                    const u16* __restrict__ W1,
                                                    u16* __restrict__ Bu){
  __shared__ __align__(16) u16 Alds[128][32];
  __shared__ __align__(16) u16 Blds[128][32];
  const int tid = threadIdx.x;
  const int bid = blockIdx.x;
  const int lid = (bid & 7) * 512 + (bid >> 3);
  const int m0 = (lid >> 3) << 7;
  const int n0 = (lid & 7) << 7;
  const int w = tid >> 6, lane = tid & 63;
  const int wm = w >> 1, wn = w & 1;
  f32x4 acc[4][4];
#pragma unroll
  for (int i = 0; i < 4; i++)
#pragma unroll
    for (int j = 0; j < 4; j++) acc[i][j] = (f32x4){0.f,0.f,0.f,0.f};

  const int srow = tid >> 1;
  const int skseg = (tid & 1) << 4;
  const float* xp = X + (size_t)(m0 + srow) * NK + skseg;
  const u16*  wp  = W1 + (size_t)(n0 + srow) * NK + skseg;

  const int klane = (lane >> 4) << 3;
  const int rowa = wm*64 + (lane & 15);
  const int rowb = wn*64 + (lane & 15);

  for (int k0 = 0; k0 < NK; k0 += 32) {
    __syncthreads();
    f32x4 v0 = *(const f32x4*)(xp + k0 + 0);
    f32x4 v1 = *(const f32x4*)(xp + k0 + 4);
    f32x4 v2 = *(const f32x4*)(xp + k0 + 8);
    f32x4 v3 = *(const f32x4*)(xp + k0 + 12);
    u32x4 q0 = *(const u32x4*)(wp + k0);
    u32x4 q1 = *(const u32x4*)(wp + k0 + 8);
    u32x4 p0, p1;
    p0[0] = pack2(v0[0], v0[1]); p0[1] = pack2(v0[2], v0[3]);
    p0[2] = pack2(v1[0], v1[1]); p0[3] = pack2(v1[2], v1[3]);
    p1[0] = pack2(v2[0], v2[1]); p1[1] = pack2(v2[2], v2[3]);
    p1[2] = pack2(v3[0], v3[1]); p1[3] = pack2(v3[2], v3[3]);
    *(u32x4*)&Alds[srow][skseg]     = p0;
    *(u32x4*)&Alds[srow][skseg + 8] = p1;
    *(u32x4*)&Blds[srow][skseg]     = q0;
    *(u32x4*)&Blds[srow][skseg + 8] = q1;
    __syncthreads();
    bf16x8 af[4], bv[4];
#pragma unroll
    for (int i = 0; i < 4; i++){
      af[i] = *(const bf16x8*)&Alds[rowa + i*16][klane];
      bv[i] = *(const bf16x8*)&Blds[rowb + i*16][klane];
    }
#pragma unroll
    for (int i = 0; i < 4; i++)
#pragma unroll
      for (int j = 0; j < 4; j++)
        acc[i][j] = __builtin_amdgcn_mfma_f32_16x16x32_bf16(af[i], bv[j], acc[i][j], 0, 0, 0);
  }

  const int r0 = (lane >> 4) << 2;
  const int col = lane & 15;
#pragma unroll
  for (int i = 0; i < 4; i++){
    int gm = m0 + wm*64 + i*16 + r0;
#pragma unroll
    for (int j = 0; j < 4; j++){
      int gn = n0 + wn*64 + j*16 + col;
#pragma unroll
      for (int r = 0; r < 4; r++)
        Bu[(size_t)(gm + r) * NN + gn] = f2bf(acc[i][j][r]);
    }
  }
}

// ---------------- scan kernels (verified rounds 2-12) ----------------

__global__ __launch_bounds__(512) void scan_carry(const u16* __restrict__ Bu,
                                                  const float* __restrict__ lam,
                                                  float* __restrict__ carry){
  const int h = threadIdx.x;
  const int bc = blockIdx.x;
  const int b = bc / NCHUNK, c = bc % NCHUNK;
  const float lre = lam[h], lim = lam[NH + h];
  float hre = 0.f, him = 0.f;
  size_t base = (size_t)(b * NL + c * CH) * NN;
  for (int j = 0; j < CH; j++){
    float bre = bf2f(Bu[base + (size_t)j*NN + h]);
    float bim = bf2f(Bu[base + (size_t)j*NN + NH + h]);
    float nre = lre*hre - lim*him + bre;
    float nim = lre*him + lim*hre + bim;
    hre = nre; him = nim;
  }
  size_t ci = ((size_t)bc * NH + h) * 2;
  carry[ci] = hre; carry[ci + 1] = him;
}

__global__ __launch_bounds__(512) void scan_combine(const float* __restrict__ carry,
                                                    const float* __restrict__ lam,
                                                    float* __restrict__ hstart){
  const int h = threadIdx.x;
  const int b = blockIdx.x;
  const float Pre = lam[2*NH + h], Pim = lam[3*NH + h];
  float are = 0.f, aim = 0.f;
  for (int c = 0; c < NCHUNK; c++){
    size_t idx = ((size_t)(b * NCHUNK + c) * NH + h) * 2;
    hstart[idx] = are; hstart[idx + 1] = aim;
    float cre = carry[idx], cim = carry[idx + 1];
    float nre = Pre*are - Pim*aim + cre;
    float nim = Pre*aim + Pim*are + cim;
    are = nre; aim = nim;
  }
}

__global__ __launch_bounds__(512) void scan_fixup_full(u16* __restrict__ Bu,
                                                       const float* __restrict__ lam,
                                                       const float* __restrict__ hstart,
                                                       float* __restrict__ out, int out_size){
  const int h = threadIdx.x;
  const int bc = blockIdx.x;
  const int b = bc / NCHUNK, c = bc % NCHUNK;
  const float lre = lam[h], lim = lam[NH + h];
  size_t si = ((size_t)bc * NH + h) * 2;
  const float sre = hstart[si], sim = hstart[si + 1];
  float hre = 0.f, him = 0.f;
  float pre = lre, pim = lim;
  size_t base = (size_t)(b * NL + c * CH) * NN;
  for (int j = 0; j < CH; j++){
    float bre = bf2f(Bu[base + (size_t)j*NN + h]);
    float bim = bf2f(Bu[base + (size_t)j*NN + NH + h]);
    float nre = lre*hre - lim*him + bre;
    float nim = lre*him + lim*hre + bim;
    hre = nre; him = nim;
    float vre = hre + pre*sre - pim*sim;
    float vim = him + pre*sim + pim*sre;
    Bu[base + (size_t)j*NN + h]      = f2bf(vre);
    Bu[base + (size_t)j*NN + NH + h] = f2bf(vim);
    if (c == NCHUNK - 1 && j == CH - 1){
      size_t ore_i = YCOUNT + (size_t)b * NH + h;
      size_t oim_i = YCOUNT + HCOUNT + (size_t)b * NH + h;
      if (ore_i < (size_t)out_size) out[ore_i] = vre;
      if (oim_i < (size_t)out_size) out[oim_i] = vim;
    }
    float qre = pre*lre - pim*lim;
    float qim = pre*lim + pim*lre;
    pre = qre; pim = qim;
  }
}

// ---------------- launch ----------------

extern "C" void kernel_launch(void* const* d_in, const int* in_sizes, int n_in,
                              void* d_out, int out_size, void* d_ws, size_t ws_size,
                              hipStream_t stream) {
  const float* x         = (const float*)d_in[0];
  const float* theta_log = (const float*)d_in[1];
  const float* nu_log    = (const float*)d_in[2];
  const float* gamma_log = (const float*)d_in[3];
  const float* Bre       = (const float*)d_in[4];
  const float* Bim       = (const float*)d_in[5];
  const float* Cre       = (const float*)d_in[6];
  const float* Cim       = (const float*)d_in[7];
  const float* Dv        = (const float*)d_in[8];
  float* out = (float*)d_out;
  char* ws = (char*)d_ws;

  // workspace layout
  u16*   W1     = (u16*)(ws);                        // 2 MiB
  u16*   W2     = (u16*)(ws + (2u << 20));           // 2 MiB
  float* lam    = (float*)(ws + (4u << 20));         // 8 KiB
  float* carry  = (float*)(ws + (5u << 20));         // 2 MiB
  float* hstart = (float*)(ws + (7u << 20));         // 2 MiB
  u16*   Bu     = (u16*)(ws + (16u << 20));          // 128 MiB
  u16*   Xb     = (u16*)(ws + (144u << 20));         // 128 MiB (fast path only)
  size_t need_base = (16u << 20) + (size_t)NM * NN * 2;           // 144 MiB
  size_t need_fast = need_base + (size_t)NM * NK * 2;             // 272 MiB
  if (ws_size < need_base) return;
  const bool fast = (ws_size >= need_fast);

  prep_w1<<<(NH * NDO + 255) / 256, 256, 0, stream>>>(Bre, Bim, gamma_log, W1);
  prep_w2<<<(NDO * NH + 255) / 256, 256, 0, stream>>>(Cre, Cim, W2);
  prep_lam<<<1, 512, 0, stream>>>(theta_log, nu_log, lam);

  if (fast) {
    convert_x<<<(int)(YCOUNT / (256*8)), 256, 0, stream>>>(x, Xb);
    gemm_sz8w<0><<<4096, 512, 0, stream>>>(Xb, W1, nullptr, nullptr, Bu, nullptr);
  } else {
    gemm1_legacy<<<4096, 256, 0, stream>>>(x, W1, Bu);
  }

  scan_carry<<<NB * NCHUNK, 512, 0, stream>>>(Bu, lam, carry);
  scan_combine<<<NB, 512, 0, stream>>>(carry, lam, hstart);
  scan_fixup_full<<<NB * NCHUNK, 512, 0, stream>>>(Bu, lam, hstart, out, out_size);

  if (fast) {
    gemm_sz8w<2><<<4096, 512, 0, stream>>>(Bu, W2, Xb, Dv, nullptr, out);
  } else {
    gemm_sz<1><<<4096, 256, 0, stream>>>(Bu, W2, x, nullptr, Dv, nullptr, out);
  }
}